// Round 1
// baseline (369.866 us; speedup 1.0000x reference)
//
#include <hip/hip_runtime.h>
#include <hip/hip_bf16.h>
#include <stdint.h>

#define DEV static __device__ __forceinline__

typedef float  f32x4  __attribute__((ext_vector_type(4)));
typedef short  bf16x8 __attribute__((ext_vector_type(8)));
typedef short  bf16x4 __attribute__((ext_vector_type(4)));
typedef short  short8 __attribute__((ext_vector_type(8)));

#if __has_builtin(__builtin_amdgcn_exp2f)
#define EXP2F(x) __builtin_amdgcn_exp2f(x)
#else
#define EXP2F(x) exp2f(x)
#endif

// fp32 -> bf16 bits, round-to-nearest-even (no NaN inputs here)
DEV short f2bf(float f) {
  union { float f; uint32_t u; } v; v.f = f;
  uint32_t u = v.u;
  u = (u + 0x7FFFu + ((u >> 16) & 1u)) >> 16;
  return (short)u;
}

// async global->LDS, 16B per lane; LDS dest = wave-uniform base + lane*16
DEV void gload16(const void* g, void* l) {
  __builtin_amdgcn_global_load_lds((const __attribute__((address_space(1))) void*)g,
                                   (__attribute__((address_space(3))) void*)l,
                                   16, 0, 0);
}

// ---------------- weight fp32 -> bf16 ----------------
__global__ void cvtw_k(const float* __restrict__ w0, const float* __restrict__ w1,
                       const float* __restrict__ w2, const float* __restrict__ w3,
                       short* __restrict__ outp)
{
  const int which = blockIdx.y;
  const float* src = which == 0 ? w0 : which == 1 ? w1 : which == 2 ? w2 : w3;
  const int idx = (blockIdx.x * 256 + threadIdx.x) * 4;
  f32x4 v = *(const f32x4*)(src + idx);
  bf16x4 o;
#pragma unroll
  for (int j = 0; j < 4; ++j) o[j] = f2bf(v[j]);
  *(bf16x4*)(outp + (size_t)which * 1048576 + idx) = o;
}

// ---------------- GEMM: C[m][n] = sum_k A[m][k]*B[n][k] + bias[n] ----------------
// M=8192, N=1024, K=1024. Tile 128x128, BK=64, 4 waves (2x2), 16x16x32 bf16 MFMA.
// MODE 0: A fp32 (reg-staged cvt), C bf16 -> [B,H,S,dk]
// MODE 1: A fp32,                  C bf16 -> [B,H,dk,S]  (transposed via LDS bounce)
// MODE 2: A bf16 (global_load_lds),C fp32 -> [M][N]      (final output)
template<int MODE>
__launch_bounds__(256, 3)
__global__ void gemm_k(const void* __restrict__ Aptr, const short* __restrict__ Bw,
                       const float* __restrict__ bias, void* __restrict__ Cout)
{
  __shared__ __align__(16) char lds[32768];
  char* AsB = lds;            // bf16 [128][64], row=128B=8 slots, slot ^= (row&7)
  char* BsB = lds + 16384;    // bf16 [128][64], same swizzle
  const int tid  = threadIdx.x;
  const int lane = tid & 63;
  const int w    = tid >> 6;
  const int wr   = w >> 1, wc = w & 1;
  const int m0   = blockIdx.y * 128;
  const int n0   = blockIdx.x * 128;
  const int lx   = lane & 15, lg = lane >> 4;

  f32x4 acc[4][4];
#pragma unroll
  for (int i = 0; i < 4; ++i)
#pragma unroll
    for (int j = 0; j < 4; ++j) acc[i][j] = 0.f;

  for (int kt = 0; kt < 16; ++kt) {
    const int k0 = kt * 64;
    // stage B (bf16) via async DMA, source pre-swizzled
#pragma unroll
    for (int i = 0; i < 4; ++i) {
      int task = i * 256 + tid;
      int row = task >> 3, sl = task & 7;
      int sg = sl ^ (row & 7);
      gload16(Bw + (size_t)(n0 + row) * 1024 + k0 + sg * 8,
              BsB + (i * 256 + w * 64) * 16);
    }
    if constexpr (MODE == 2) {
      const short* Ab = (const short*)Aptr;
#pragma unroll
      for (int i = 0; i < 4; ++i) {
        int task = i * 256 + tid;
        int row = task >> 3, sl = task & 7;
        int sg = sl ^ (row & 7);
        gload16(Ab + (size_t)(m0 + row) * 1024 + k0 + sg * 8,
                AsB + (i * 256 + w * 64) * 16);
      }
    } else {
      // reg-stage A fp32 -> bf16 into swizzled LDS
      const float* Af = (const float*)Aptr;
      f32x4 t0[4], t1[4];
#pragma unroll
      for (int i = 0; i < 4; ++i) {
        int task = i * 256 + tid;
        int row = task >> 3, osl = task & 7;
        const float* src = Af + (size_t)(m0 + row) * 1024 + k0 + osl * 8;
        t0[i] = *(const f32x4*)src;
        t1[i] = *(const f32x4*)(src + 4);
      }
#pragma unroll
      for (int i = 0; i < 4; ++i) {
        int task = i * 256 + tid;
        int row = task >> 3, osl = task & 7;
        bf16x8 vv;
#pragma unroll
        for (int j = 0; j < 4; ++j) vv[j] = f2bf(t0[i][j]);
#pragma unroll
        for (int j = 0; j < 4; ++j) vv[4 + j] = f2bf(t1[i][j]);
        *(bf16x8*)(AsB + row * 128 + ((osl ^ (row & 7)) * 16)) = vv;
      }
    }
    __syncthreads();   // drains vmcnt (global_load_lds) + lds writes visible
#pragma unroll
    for (int ks = 0; ks < 2; ++ks) {
      bf16x8 av[4], bv[4];
#pragma unroll
      for (int mf = 0; mf < 4; ++mf) {
        int ar = wr * 64 + mf * 16 + lx;
        int sl = (ks * 4 + lg) ^ (ar & 7);
        av[mf] = *(const bf16x8*)(AsB + ar * 128 + sl * 16);
      }
#pragma unroll
      for (int nf = 0; nf < 4; ++nf) {
        int br = wc * 64 + nf * 16 + lx;
        int sl = (ks * 4 + lg) ^ (br & 7);
        bv[nf] = *(const bf16x8*)(BsB + br * 128 + sl * 16);
      }
#pragma unroll
      for (int mf = 0; mf < 4; ++mf)
#pragma unroll
        for (int nf = 0; nf < 4; ++nf)
          acc[mf][nf] = __builtin_amdgcn_mfma_f32_16x16x32_bf16(av[mf], bv[nf], acc[mf][nf], 0, 0, 0);
    }
    __syncthreads();
  }

  if constexpr (MODE == 0 || MODE == 2) {
#pragma unroll
    for (int mf = 0; mf < 4; ++mf)
#pragma unroll
      for (int nf = 0; nf < 4; ++nf) {
        int gn = n0 + wc * 64 + nf * 16 + lx;
        float bvl = bias[gn];
#pragma unroll
        for (int r = 0; r < 4; ++r) {
          int gm = m0 + wr * 64 + mf * 16 + lg * 4 + r;
          float val = acc[mf][nf][r] + bvl;
          if constexpr (MODE == 0) {
            int bb = gm >> 11, s = gm & 2047, h = gn >> 6, dk = gn & 63;
            ((short*)Cout)[((size_t)(bb * 16 + h) << 17) + ((size_t)s << 6) + dk] = f2bf(val);
          } else {
            ((float*)Cout)[((size_t)gm << 10) + gn] = val;
          }
        }
      }
  } else {
    // MODE 1: transpose quadrant via per-wave LDS region, store coalesced [B,H,dk,S]
    short* wl = (short*)(void*)lds + w * 4096;  // [64 n][64 m]
#pragma unroll
    for (int mf = 0; mf < 4; ++mf)
#pragma unroll
      for (int nf = 0; nf < 4; ++nf) {
        int nl = nf * 16 + lx;
        float bvl = bias[n0 + wc * 64 + nl];
#pragma unroll
        for (int r = 0; r < 4; ++r) {
          int ml = mf * 16 + lg * 4 + r;
          wl[nl * 64 + ml] = f2bf(acc[mf][nf][r] + bvl);
        }
      }
    short* Cs = (short*)Cout;
#pragma unroll
    for (int p = 0; p < 8; ++p) {
      int d  = p * 8 + (lane >> 3);
      int mm = (lane & 7) * 8;
      bf16x4 lo = *(const bf16x4*)(wl + d * 64 + mm);
      bf16x4 hi = *(const bf16x4*)(wl + d * 64 + mm + 4);
      int gn = n0 + wc * 64 + d;
      int h = gn >> 6, dk = gn & 63;
      int gm = m0 + wr * 64 + mm;
      int bb = gm >> 11, s = gm & 2047;
      short8 val = { lo[0], lo[1], lo[2], lo[3], hi[0], hi[1], hi[2], hi[3] };
      *(short8*)(Cs + ((size_t)(bb * 16 + h) << 17) + ((size_t)dk << 11) + s) = val;
    }
  }
}

// ---------------- flash attention ----------------
// grid (16 q-tiles, 64 bh). Q [B,H,S,64], K [B,H,S,64], Vt [B,H,64,S] (all bf16).
// Block: 128 q-rows, 4 waves x 32 rows. KV tile = 64.
__launch_bounds__(256, 3)
__global__ void attn_k(const short* __restrict__ Qb, const short* __restrict__ Kb,
                       const short* __restrict__ Vtb, short* __restrict__ Xb)
{
  __shared__ __align__(16) char lds[8192 + 8192 + 128 * 72 * 2];
  char*  Klds = lds;                       // [64 kv][64 d] swz (row&7)
  char*  Vlds = lds + 8192;                // [64 d][64 kv] swz (row&7)
  short* Plds = (short*)(void*)(lds + 16384); // [128 q][72]
  const int tid = threadIdx.x, lane = tid & 63, w = tid >> 6;
  const int lx = lane & 15, lg = lane >> 4;
  const int bh = blockIdx.y;
  const int q0 = blockIdx.x * 128;
  const size_t base = (size_t)bh << 17;    // *131072

  bf16x8 aq[2][2];
#pragma unroll
  for (int m = 0; m < 2; ++m)
#pragma unroll
    for (int ks = 0; ks < 2; ++ks)
      aq[m][ks] = *(const bf16x8*)(Qb + base + (size_t)(q0 + w * 32 + m * 16 + lx) * 64 + ks * 32 + lg * 8);

  f32x4 o[2][4];
  float mrun[2][4], lrun[2][4];
#pragma unroll
  for (int m = 0; m < 2; ++m) {
#pragma unroll
    for (int df = 0; df < 4; ++df) o[m][df] = 0.f;
#pragma unroll
    for (int r = 0; r < 4; ++r) { mrun[m][r] = -1e30f; lrun[m][r] = 0.f; }
  }
  const float SC = 0.18033688011112042f;   // log2(e)/sqrt(64)

  for (int kt = 0; kt < 32; ++kt) {
    const int kv0 = kt * 64;
#pragma unroll
    for (int i = 0; i < 2; ++i) {
      int task = i * 256 + tid;
      int row = task >> 3, sl = task & 7, sg = sl ^ (row & 7);
      gload16(Kb + base + (size_t)(kv0 + row) * 64 + sg * 8, Klds + (i * 256 + w * 64) * 16);
    }
#pragma unroll
    for (int i = 0; i < 2; ++i) {
      int task = i * 256 + tid;
      int row = task >> 3, sl = task & 7, sg = sl ^ (row & 7);
      gload16(Vtb + base + (size_t)row * 2048 + kv0 + sg * 8, Vlds + (i * 256 + w * 64) * 16);
    }
    __syncthreads();

    // S = Q K^T   (rows q, cols kv)
    f32x4 sc[2][4];
#pragma unroll
    for (int m = 0; m < 2; ++m)
#pragma unroll
      for (int nf = 0; nf < 4; ++nf) sc[m][nf] = 0.f;
#pragma unroll
    for (int ks = 0; ks < 2; ++ks) {
      bf16x8 bk[4];
#pragma unroll
      for (int nf = 0; nf < 4; ++nf) {
        int kr = nf * 16 + lx;
        int sl = (ks * 4 + lg) ^ (kr & 7);
        bk[nf] = *(const bf16x8*)(Klds + kr * 128 + sl * 16);
      }
#pragma unroll
      for (int m = 0; m < 2; ++m)
#pragma unroll
        for (int nf = 0; nf < 4; ++nf)
          sc[m][nf] = __builtin_amdgcn_mfma_f32_16x16x32_bf16(aq[m][ks], bk[nf], sc[m][nf], 0, 0, 0);
    }

    // online softmax (exp2 domain), wave-parallel row reduce over 16 lanes
#pragma unroll
    for (int m = 0; m < 2; ++m)
#pragma unroll
      for (int r = 0; r < 4; ++r) {
        float mx = fmaxf(fmaxf(sc[m][0][r], sc[m][1][r]), fmaxf(sc[m][2][r], sc[m][3][r]));
        mx = fmaxf(mx, __shfl_xor(mx, 1));
        mx = fmaxf(mx, __shfl_xor(mx, 2));
        mx = fmaxf(mx, __shfl_xor(mx, 4));
        mx = fmaxf(mx, __shfl_xor(mx, 8));
        mx *= SC;
        float mn = fmaxf(mrun[m][r], mx);
        float al = EXP2F(mrun[m][r] - mn);
        float rs = 0.f;
#pragma unroll
        for (int nf = 0; nf < 4; ++nf) {
          float p = EXP2F(sc[m][nf][r] * SC - mn);
          sc[m][nf][r] = p;
          rs += p;
        }
        rs += __shfl_xor(rs, 1);
        rs += __shfl_xor(rs, 2);
        rs += __shfl_xor(rs, 4);
        rs += __shfl_xor(rs, 8);
        mrun[m][r] = mn;
        lrun[m][r] = lrun[m][r] * al + rs;
#pragma unroll
        for (int df = 0; df < 4; ++df) o[m][df][r] *= al;
      }

    // P -> LDS (bf16), rows owned per-wave
#pragma unroll
    for (int m = 0; m < 2; ++m)
#pragma unroll
      for (int nf = 0; nf < 4; ++nf)
#pragma unroll
        for (int r = 0; r < 4; ++r)
          Plds[(w * 32 + m * 16 + lg * 4 + r) * 72 + nf * 16 + lx] = f2bf(sc[m][nf][r]);

    // O += P V   (A from P rows, B from Vt rows)
#pragma unroll
    for (int ks = 0; ks < 2; ++ks) {
      bf16x8 pa[2], bvv[4];
#pragma unroll
      for (int m = 0; m < 2; ++m)
        pa[m] = *(const bf16x8*)((const char*)Plds + (size_t)(w * 32 + m * 16 + lx) * 144 + ks * 64 + lg * 16);
#pragma unroll
      for (int df = 0; df < 4; ++df) {
        int dr = df * 16 + lx;
        int sl = (ks * 4 + lg) ^ (dr & 7);
        bvv[df] = *(const bf16x8*)(Vlds + dr * 128 + sl * 16);
      }
#pragma unroll
      for (int m = 0; m < 2; ++m)
#pragma unroll
        for (int df = 0; df < 4; ++df)
          o[m][df] = __builtin_amdgcn_mfma_f32_16x16x32_bf16(pa[m], bvv[df], o[m][df], 0, 0, 0);
    }
    __syncthreads();
  }

  // epilogue: O / l  -> X [B,S,1024] bf16 (merged heads)
  const int bb = bh >> 4, h = bh & 15;
#pragma unroll
  for (int m = 0; m < 2; ++m)
#pragma unroll
    for (int r = 0; r < 4; ++r) {
      float inv = 1.0f / lrun[m][r];
      int gs = q0 + w * 32 + m * 16 + lg * 4 + r;
      size_t rowb = ((size_t)(bb * 2048 + gs)) << 10;
#pragma unroll
      for (int df = 0; df < 4; ++df)
        Xb[rowb + h * 64 + df * 16 + lx] = f2bf(o[m][df][r] * inv);
    }
}

// ---------------- host ----------------
extern "C" void kernel_launch(void* const* d_in, const int* in_sizes, int n_in,
                              void* d_out, int out_size, void* d_ws, size_t ws_size,
                              hipStream_t stream)
{
  (void)in_sizes; (void)n_in; (void)out_size; (void)ws_size;
  const float* q  = (const float*)d_in[0];
  const float* k  = (const float*)d_in[1];
  const float* v  = (const float*)d_in[2];
  const float* Wq = (const float*)d_in[3];
  const float* bq = (const float*)d_in[4];
  const float* Wk = (const float*)d_in[5];
  const float* bk = (const float*)d_in[6];
  const float* Wv = (const float*)d_in[7];
  const float* bv = (const float*)d_in[8];
  const float* Wo = (const float*)d_in[9];
  const float* bo = (const float*)d_in[10];

  short* ws  = (short*)d_ws;
  short* wqb = ws;                  // 1024*1024 each
  short* wkb = wqb + 1048576;
  short* wvb = wkb + 1048576;
  short* wob = wvb + 1048576;
  short* Qb  = wob + 1048576;       // 8192*1024 each
  short* Kb  = Qb  + 8388608;
  short* Vtb = Kb  + 8388608;
  short* Xb  = Vtb + 8388608;       // total 75,497,472 bytes

  cvtw_k<<<dim3(1024, 4), 256, 0, stream>>>(Wq, Wk, Wv, Wo, wqb);
  gemm_k<0><<<dim3(8, 64), 256, 0, stream>>>(q, wqb, bq, Qb);
  gemm_k<0><<<dim3(8, 64), 256, 0, stream>>>(k, wkb, bk, Kb);
  gemm_k<1><<<dim3(8, 64), 256, 0, stream>>>(v, wvb, bv, Vtb);
  attn_k<<<dim3(16, 64), 256, 0, stream>>>(Qb, Kb, Vtb, Xb);
  gemm_k<2><<<dim3(8, 64), 256, 0, stream>>>(Xb, wob, bo, d_out);
}

// Round 2
// 324.944 us; speedup vs baseline: 1.1382x; 1.1382x over previous
//
#include <hip/hip_runtime.h>
#include <hip/hip_bf16.h>
#include <stdint.h>

#define DEV static __device__ __forceinline__

typedef float  f32x4  __attribute__((ext_vector_type(4)));
typedef short  bf16x8 __attribute__((ext_vector_type(8)));
typedef short  bf16x4 __attribute__((ext_vector_type(4)));
typedef short  short8 __attribute__((ext_vector_type(8)));

#if __has_builtin(__builtin_amdgcn_exp2f)
#define EXP2F(x) __builtin_amdgcn_exp2f(x)
#else
#define EXP2F(x) exp2f(x)
#endif

// fp32 -> bf16 bits, round-to-nearest-even (no NaN inputs here)
DEV short f2bf(float f) {
  union { float f; uint32_t u; } v; v.f = f;
  uint32_t u = v.u;
  u = (u + 0x7FFFu + ((u >> 16) & 1u)) >> 16;
  return (short)u;
}

DEV f32x4 vmax4(f32x4 a, f32x4 b) {
  f32x4 r;
  r[0] = fmaxf(a[0], b[0]); r[1] = fmaxf(a[1], b[1]);
  r[2] = fmaxf(a[2], b[2]); r[3] = fmaxf(a[3], b[3]);
  return r;
}

// async global->LDS, 16B per lane; LDS dest = wave-uniform base + lane*16
DEV void gload16(const void* g, void* l) {
  __builtin_amdgcn_global_load_lds((const __attribute__((address_space(1))) void*)g,
                                   (__attribute__((address_space(3))) void*)l,
                                   16, 0, 0);
}

// ---------------- weight fp32 -> bf16 ----------------
__global__ void cvtw_k(const float* __restrict__ w0, const float* __restrict__ w1,
                       const float* __restrict__ w2, const float* __restrict__ w3,
                       short* __restrict__ outp)
{
  const int which = blockIdx.y;
  const float* src = which == 0 ? w0 : which == 1 ? w1 : which == 2 ? w2 : w3;
  const int idx = (blockIdx.x * 256 + threadIdx.x) * 4;
  f32x4 v = *(const f32x4*)(src + idx);
  bf16x4 o;
#pragma unroll
  for (int j = 0; j < 4; ++j) o[j] = f2bf(v[j]);
  *(bf16x4*)(outp + (size_t)which * 1048576 + idx) = o;
}

// ---------------- GEMM: C[m][n] = sum_k A[m][k]*B[n][k] + bias[n] ----------------
// M=8192, N=1024, K=1024. Tile 128x128, BK=64, 4 waves (2x2), 16x16x32 bf16 MFMA.
// MODE 0: A fp32 (reg-staged cvt), C bf16 -> [B,H,S,dk]
// MODE 1: A fp32,                  C bf16 -> [B,H,dk,S]  (transposed via LDS bounce)
// MODE 2: A bf16 (global_load_lds),C fp32 -> [M][N]      (final output)
template<int MODE>
__launch_bounds__(256, 3)
__global__ void gemm_k(const void* __restrict__ Aptr, const short* __restrict__ Bw,
                       const float* __restrict__ bias, void* __restrict__ Cout)
{
  __shared__ __align__(16) char lds[32768];
  char* AsB = lds;            // bf16 [128][64], row=128B=8 slots, slot ^= (row&7)
  char* BsB = lds + 16384;    // bf16 [128][64], same swizzle
  const int tid  = threadIdx.x;
  const int lane = tid & 63;
  const int w    = tid >> 6;
  const int wr   = w >> 1, wc = w & 1;
  const int m0   = blockIdx.y * 128;
  const int n0   = blockIdx.x * 128;
  const int lx   = lane & 15, lg = lane >> 4;

  f32x4 acc[4][4];
#pragma unroll
  for (int i = 0; i < 4; ++i)
#pragma unroll
    for (int j = 0; j < 4; ++j) acc[i][j] = 0.f;

  for (int kt = 0; kt < 16; ++kt) {
    const int k0 = kt * 64;
    // stage B (bf16) via async DMA, source pre-swizzled
#pragma unroll
    for (int i = 0; i < 4; ++i) {
      int task = i * 256 + tid;
      int row = task >> 3, sl = task & 7;
      int sg = sl ^ (row & 7);
      gload16(Bw + (size_t)(n0 + row) * 1024 + k0 + sg * 8,
              BsB + (i * 256 + w * 64) * 16);
    }
    if constexpr (MODE == 2) {
      const short* Ab = (const short*)Aptr;
#pragma unroll
      for (int i = 0; i < 4; ++i) {
        int task = i * 256 + tid;
        int row = task >> 3, sl = task & 7;
        int sg = sl ^ (row & 7);
        gload16(Ab + (size_t)(m0 + row) * 1024 + k0 + sg * 8,
                AsB + (i * 256 + w * 64) * 16);
      }
    } else {
      // reg-stage A fp32 -> bf16 into swizzled LDS
      const float* Af = (const float*)Aptr;
      f32x4 t0[4], t1[4];
#pragma unroll
      for (int i = 0; i < 4; ++i) {
        int task = i * 256 + tid;
        int row = task >> 3, osl = task & 7;
        const float* src = Af + (size_t)(m0 + row) * 1024 + k0 + osl * 8;
        t0[i] = *(const f32x4*)src;
        t1[i] = *(const f32x4*)(src + 4);
      }
#pragma unroll
      for (int i = 0; i < 4; ++i) {
        int task = i * 256 + tid;
        int row = task >> 3, osl = task & 7;
        bf16x8 vv;
#pragma unroll
        for (int j = 0; j < 4; ++j) vv[j] = f2bf(t0[i][j]);
#pragma unroll
        for (int j = 0; j < 4; ++j) vv[4 + j] = f2bf(t1[i][j]);
        *(bf16x8*)(AsB + row * 128 + ((osl ^ (row & 7)) * 16)) = vv;
      }
    }
    __syncthreads();   // drains vmcnt (global_load_lds) + lds writes visible
#pragma unroll
    for (int ks = 0; ks < 2; ++ks) {
      bf16x8 av[4], bv[4];
#pragma unroll
      for (int mf = 0; mf < 4; ++mf) {
        int ar = wr * 64 + mf * 16 + lx;
        int sl = (ks * 4 + lg) ^ (ar & 7);
        av[mf] = *(const bf16x8*)(AsB + ar * 128 + sl * 16);
      }
#pragma unroll
      for (int nf = 0; nf < 4; ++nf) {
        int br = wc * 64 + nf * 16 + lx;
        int sl = (ks * 4 + lg) ^ (br & 7);
        bv[nf] = *(const bf16x8*)(BsB + br * 128 + sl * 16);
      }
#pragma unroll
      for (int mf = 0; mf < 4; ++mf)
#pragma unroll
        for (int nf = 0; nf < 4; ++nf)
          acc[mf][nf] = __builtin_amdgcn_mfma_f32_16x16x32_bf16(av[mf], bv[nf], acc[mf][nf], 0, 0, 0);
    }
    __syncthreads();
  }

  if constexpr (MODE == 0 || MODE == 2) {
#pragma unroll
    for (int mf = 0; mf < 4; ++mf)
#pragma unroll
      for (int nf = 0; nf < 4; ++nf) {
        int gn = n0 + wc * 64 + nf * 16 + lx;
        float bvl = bias[gn];
#pragma unroll
        for (int r = 0; r < 4; ++r) {
          int gm = m0 + wr * 64 + mf * 16 + lg * 4 + r;
          float val = acc[mf][nf][r] + bvl;
          if constexpr (MODE == 0) {
            int bb = gm >> 11, s = gm & 2047, h = gn >> 6, dk = gn & 63;
            ((short*)Cout)[((size_t)(bb * 16 + h) << 17) + ((size_t)s << 6) + dk] = f2bf(val);
          } else {
            ((float*)Cout)[((size_t)gm << 10) + gn] = val;
          }
        }
      }
  } else {
    // MODE 1: transpose quadrant via per-wave LDS region, store coalesced [B,H,dk,S]
    short* wl = (short*)(void*)lds + w * 4096;  // [64 n][64 m]
#pragma unroll
    for (int mf = 0; mf < 4; ++mf)
#pragma unroll
      for (int nf = 0; nf < 4; ++nf) {
        int nl = nf * 16 + lx;
        float bvl = bias[n0 + wc * 64 + nl];
#pragma unroll
        for (int r = 0; r < 4; ++r) {
          int ml = mf * 16 + lg * 4 + r;
          wl[nl * 64 + ml] = f2bf(acc[mf][nf][r] + bvl);
        }
      }
    short* Cs = (short*)Cout;
#pragma unroll
    for (int p = 0; p < 8; ++p) {
      int d  = p * 8 + (lane >> 3);
      int mm = (lane & 7) * 8;
      bf16x4 lo = *(const bf16x4*)(wl + d * 64 + mm);
      bf16x4 hi = *(const bf16x4*)(wl + d * 64 + mm + 4);
      int gn = n0 + wc * 64 + d;
      int h = gn >> 6, dk = gn & 63;
      int gm = m0 + wr * 64 + mm;
      int bb = gm >> 11, s = gm & 2047;
      short8 val = { lo[0], lo[1], lo[2], lo[3], hi[0], hi[1], hi[2], hi[3] };
      *(short8*)(Cs + ((size_t)(bb * 16 + h) << 17) + ((size_t)dk << 11) + s) = val;
    }
  }
}

// ---------------- flash attention ----------------
// grid (16 q-tiles, 64 bh). Q [B,H,S,64], K [B,H,S,64], Vt [B,H,64,S] (all bf16).
// Block: 128 q-rows, 4 waves x 32 rows. KV tile = 64, K/V double-buffered.
// Softmax: wave-global running max (scalar) + row-sums via all-ones-B MFMA.
__launch_bounds__(256, 3)
__global__ void attn_k(const short* __restrict__ Qb, const short* __restrict__ Kb,
                       const short* __restrict__ Vtb, short* __restrict__ Xb)
{
  __shared__ __align__(16) char lds[49152];
  // K: lds + buf*8192        [64 kv][64 d] bf16, slot ^= (row&7)
  // V: lds + 16384 + buf*8192 [64 d][64 kv] bf16, same swizzle
  // P: lds + 32768            [128 q][64 kv] bf16, same swizzle
  char* Pb = lds + 32768;
  const int tid = threadIdx.x, lane = tid & 63, w = tid >> 6;
  const int lx = lane & 15, lg = lane >> 4;
  const int bh = blockIdx.y;
  const int q0 = blockIdx.x * 128;
  const size_t base = (size_t)bh << 17;    // *131072

  bf16x8 aq[2][2];
#pragma unroll
  for (int m = 0; m < 2; ++m)
#pragma unroll
    for (int ks = 0; ks < 2; ++ks)
      aq[m][ks] = *(const bf16x8*)(Qb + base + (size_t)(q0 + w * 32 + m * 16 + lx) * 64 + ks * 32 + lg * 8);

  f32x4 o[2][4];
  f32x4 lrun[2];
  float mrun = -1e30f;
#pragma unroll
  for (int m = 0; m < 2; ++m) {
#pragma unroll
    for (int df = 0; df < 4; ++df) o[m][df] = 0.f;
    lrun[m] = 0.f;
  }
  const float SC = 0.18033688011112042f;   // log2(e)/sqrt(64)
  const bf16x8 vones = { 0x3F80, 0x3F80, 0x3F80, 0x3F80, 0x3F80, 0x3F80, 0x3F80, 0x3F80 };

  // prologue: stage tile 0 into buf 0
#pragma unroll
  for (int i = 0; i < 2; ++i) {
    int task = i * 256 + tid;
    int row = task >> 3, sl = task & 7, sg = sl ^ (row & 7);
    gload16(Kb + base + (size_t)row * 64 + sg * 8, lds + (i * 256 + w * 64) * 16);
    gload16(Vtb + base + (size_t)row * 2048 + sg * 8, lds + 16384 + (i * 256 + w * 64) * 16);
  }
  __syncthreads();

  for (int kt = 0; kt < 32; ++kt) {
    char* Kcur = lds + (kt & 1) * 8192;
    char* Vcur = lds + 16384 + (kt & 1) * 8192;
    // stage next tile into other buffer (drained by the barrier at tile end)
    if (kt < 31) {
      const int kv1 = (kt + 1) * 64;
      char* Knxt = lds + ((kt + 1) & 1) * 8192;
      char* Vnxt = lds + 16384 + ((kt + 1) & 1) * 8192;
#pragma unroll
      for (int i = 0; i < 2; ++i) {
        int task = i * 256 + tid;
        int row = task >> 3, sl = task & 7, sg = sl ^ (row & 7);
        gload16(Kb + base + (size_t)(kv1 + row) * 64 + sg * 8, Knxt + (i * 256 + w * 64) * 16);
        gload16(Vtb + base + (size_t)row * 2048 + kv1 + sg * 8, Vnxt + (i * 256 + w * 64) * 16);
      }
    }

    // S = Q K^T   (rows q, cols kv)
    f32x4 sc[2][4];
#pragma unroll
    for (int m = 0; m < 2; ++m)
#pragma unroll
      for (int nf = 0; nf < 4; ++nf) sc[m][nf] = 0.f;
#pragma unroll
    for (int ks = 0; ks < 2; ++ks) {
      bf16x8 bk[4];
#pragma unroll
      for (int nf = 0; nf < 4; ++nf) {
        int kr = nf * 16 + lx;
        int sl = (ks * 4 + lg) ^ (kr & 7);
        bk[nf] = *(const bf16x8*)(Kcur + kr * 128 + sl * 16);
      }
#pragma unroll
      for (int m = 0; m < 2; ++m)
#pragma unroll
        for (int nf = 0; nf < 4; ++nf)
          sc[m][nf] = __builtin_amdgcn_mfma_f32_16x16x32_bf16(aq[m][ks], bk[nf], sc[m][nf], 0, 0, 0);
    }

    // wave-global tile max (upper-bounds every row max in this wave)
    f32x4 v0 = vmax4(sc[0][0], sc[0][1]);
    f32x4 v1 = vmax4(sc[0][2], sc[0][3]);
    f32x4 v2 = vmax4(sc[1][0], sc[1][1]);
    f32x4 v3 = vmax4(sc[1][2], sc[1][3]);
    v0 = vmax4(vmax4(v0, v1), vmax4(v2, v3));
    float mx = fmaxf(fmaxf(v0[0], v0[1]), fmaxf(v0[2], v0[3]));
    mx = fmaxf(mx, __shfl_xor(mx, 1));
    mx = fmaxf(mx, __shfl_xor(mx, 2));
    mx = fmaxf(mx, __shfl_xor(mx, 4));
    mx = fmaxf(mx, __shfl_xor(mx, 8));
    mx = fmaxf(mx, __shfl_xor(mx, 16));
    mx = fmaxf(mx, __shfl_xor(mx, 32));
    mx *= SC;
    const float mn = fmaxf(mrun, mx);
    const float al = EXP2F(mrun - mn);
    mrun = mn;
    if (al < 1.0f) {   // wave-uniform: rescale only when max grew
#pragma unroll
      for (int m = 0; m < 2; ++m) {
#pragma unroll
        for (int df = 0; df < 4; ++df) o[m][df] *= al;
        lrun[m] *= al;
      }
    }
    const float nm = -mn;

    // P = exp2(S*SC - mn) -> bf16 -> Plds (XOR-swizzled rows, wave-private)
#pragma unroll
    for (int m = 0; m < 2; ++m)
#pragma unroll
      for (int nf = 0; nf < 4; ++nf) {
        f32x4 p;
#pragma unroll
        for (int r = 0; r < 4; ++r) p[r] = EXP2F(sc[m][nf][r] * SC + nm);
#pragma unroll
        for (int r = 0; r < 4; ++r) {
          int row = w * 32 + m * 16 + lg * 4 + r;
          int slot = (nf * 2 + (lx >> 3)) ^ (row & 7);
          *(short*)(Pb + row * 128 + slot * 16 + (lx & 7) * 2) = f2bf(p[r]);
        }
      }

    // O += P V ; row-sums via all-ones B fragment
    f32x4 rs0 = 0.f, rs1 = 0.f;
#pragma unroll
    for (int ks = 0; ks < 2; ++ks) {
      bf16x8 pa[2], bvv[4];
#pragma unroll
      for (int m = 0; m < 2; ++m) {
        int row = w * 32 + m * 16 + lx;
        int sl = (ks * 4 + lg) ^ (row & 7);
        pa[m] = *(const bf16x8*)(Pb + row * 128 + sl * 16);
      }
#pragma unroll
      for (int df = 0; df < 4; ++df) {
        int dr = df * 16 + lx;
        int sl = (ks * 4 + lg) ^ (dr & 7);
        bvv[df] = *(const bf16x8*)(Vcur + dr * 128 + sl * 16);
      }
      rs0 = __builtin_amdgcn_mfma_f32_16x16x32_bf16(pa[0], vones, rs0, 0, 0, 0);
      rs1 = __builtin_amdgcn_mfma_f32_16x16x32_bf16(pa[1], vones, rs1, 0, 0, 0);
#pragma unroll
      for (int m = 0; m < 2; ++m)
#pragma unroll
        for (int df = 0; df < 4; ++df)
          o[m][df] = __builtin_amdgcn_mfma_f32_16x16x32_bf16(pa[m], bvv[df], o[m][df], 0, 0, 0);
    }
    lrun[0] += rs0;
    lrun[1] += rs1;

    __syncthreads();   // staged next tile complete + all waves done with cur bufs
  }

  // epilogue: O / l  -> X [B,S,1024] bf16 (merged heads)
  const int bb = bh >> 4, h = bh & 15;
#pragma unroll
  for (int m = 0; m < 2; ++m)
#pragma unroll
    for (int r = 0; r < 4; ++r) {
      float inv = 1.0f / lrun[m][r];
      int gs = q0 + w * 32 + m * 16 + lg * 4 + r;
      size_t rowb = ((size_t)(bb * 2048 + gs)) << 10;
#pragma unroll
      for (int df = 0; df < 4; ++df)
        Xb[rowb + h * 64 + df * 16 + lx] = f2bf(o[m][df][r] * inv);
    }
}

// ---------------- host ----------------
extern "C" void kernel_launch(void* const* d_in, const int* in_sizes, int n_in,
                              void* d_out, int out_size, void* d_ws, size_t ws_size,
                              hipStream_t stream)
{
  (void)in_sizes; (void)n_in; (void)out_size; (void)ws_size;
  const float* q  = (const float*)d_in[0];
  const float* k  = (const float*)d_in[1];
  const float* v  = (const float*)d_in[2];
  const float* Wq = (const float*)d_in[3];
  const float* bq = (const float*)d_in[4];
  const float* Wk = (const float*)d_in[5];
  const float* bk = (const float*)d_in[6];
  const float* Wv = (const float*)d_in[7];
  const float* bv = (const float*)d_in[8];
  const float* Wo = (const float*)d_in[9];
  const float* bo = (const float*)d_in[10];

  short* ws  = (short*)d_ws;
  short* wqb = ws;                  // 1024*1024 each
  short* wkb = wqb + 1048576;
  short* wvb = wkb + 1048576;
  short* wob = wvb + 1048576;
  short* Qb  = wob + 1048576;       // 8192*1024 each
  short* Kb  = Qb  + 8388608;
  short* Vtb = Kb  + 8388608;
  short* Xb  = Vtb + 8388608;       // total 75,497,472 bytes

  cvtw_k<<<dim3(1024, 4), 256, 0, stream>>>(Wq, Wk, Wv, Wo, wqb);
  gemm_k<0><<<dim3(8, 64), 256, 0, stream>>>(q, wqb, bq, Qb);
  gemm_k<0><<<dim3(8, 64), 256, 0, stream>>>(k, wkb, bk, Kb);
  gemm_k<1><<<dim3(8, 64), 256, 0, stream>>>(v, wvb, bv, Vtb);
  attn_k<<<dim3(16, 64), 256, 0, stream>>>(Qb, Kb, Vtb, Xb);
  gemm_k<2><<<dim3(8, 64), 256, 0, stream>>>(Xb, wob, bo, d_out);
}

// Round 3
// 253.101 us; speedup vs baseline: 1.4613x; 1.2839x over previous
//
#include <hip/hip_runtime.h>
#include <hip/hip_bf16.h>
#include <stdint.h>

#define DEV static __device__ __forceinline__

typedef float    f32x4  __attribute__((ext_vector_type(4)));
typedef short    bf16x8 __attribute__((ext_vector_type(8)));
typedef short    bf16x4 __attribute__((ext_vector_type(4)));
typedef short    short8 __attribute__((ext_vector_type(8)));
typedef uint32_t u32x4  __attribute__((ext_vector_type(4)));

#if __has_builtin(__builtin_amdgcn_exp2f)
#define EXP2F(x) __builtin_amdgcn_exp2f(x)
#else
#define EXP2F(x) exp2f(x)
#endif

// fp32 -> bf16 bits, round-to-nearest-even (epilogue-only; hot paths use cvt_pk)
DEV short f2bf(float f) {
  union { float f; uint32_t u; } v; v.f = f;
  uint32_t u = v.u;
  u = (u + 0x7FFFu + ((u >> 16) & 1u)) >> 16;
  return (short)u;
}

// two f32 -> packed 2x bf16 (RNE), single instruction
DEV uint32_t cvtpk(float lo, float hi) {
  uint32_t r;
  asm("v_cvt_pk_bf16_f32 %0, %1, %2" : "=v"(r) : "v"(lo), "v"(hi));
  return r;
}

DEV f32x4 vmax4(f32x4 a, f32x4 b) {
  f32x4 r;
  r[0] = fmaxf(a[0], b[0]); r[1] = fmaxf(a[1], b[1]);
  r[2] = fmaxf(a[2], b[2]); r[3] = fmaxf(a[3], b[3]);
  return r;
}

// async global->LDS, 16B per lane; LDS dest = wave-uniform base + lane*16
DEV void gload16(const void* g, void* l) {
  __builtin_amdgcn_global_load_lds((const __attribute__((address_space(1))) void*)g,
                                   (__attribute__((address_space(3))) void*)l,
                                   16, 0, 0);
}

// ---------------- weight fp32 -> bf16 ----------------
__global__ void cvtw_k(const float* __restrict__ w0, const float* __restrict__ w1,
                       const float* __restrict__ w2, const float* __restrict__ w3,
                       short* __restrict__ outp)
{
  const int which = blockIdx.y;
  const float* src = which == 0 ? w0 : which == 1 ? w1 : which == 2 ? w2 : w3;
  const int idx = (blockIdx.x * 256 + threadIdx.x) * 4;
  f32x4 v = *(const f32x4*)(src + idx);
  bf16x4 o;
#pragma unroll
  for (int j = 0; j < 4; ++j) o[j] = f2bf(v[j]);
  *(bf16x4*)(outp + (size_t)which * 1048576 + idx) = o;
}

// ---------------- GEMM: C[m][n] = (sum_k A[m][k]*B[n][k] + bias[n]) * scl ----------------
// M=8192, N=1024, K=1024. Tile 128x128, BK=64, 4 waves (2x2), 16x16x32 bf16 MFMA.
// 2-phase pipeline: issue next-tile loads (B: global_load_lds dbuf; A: global->reg),
// compute current, barrier, write A(t+1) to LDS (cvt_pk), barrier.
// Grid: 1-D 512 blocks, XCD-swizzled so the 8 n-blocks sharing an A-row-panel
// land on one XCD (A panel stays in that XCD's L2).
// MODE 0: A fp32, C bf16 -> [B,H,S,dk]
// MODE 1: A fp32, C bf16 -> [B,H,dk,S]  (transposed via LDS bounce)
// MODE 2: A bf16, C fp32 -> [M][N]
template<int MODE>
__launch_bounds__(256, 3)
__global__ void gemm_k(const void* __restrict__ Aptr, const short* __restrict__ Bw,
                       const float* __restrict__ bias, void* __restrict__ Cout,
                       float scl)
{
  __shared__ __align__(16) char lds[49152];
  char* AsB  = lds;            // bf16 [128][64], row=128B=8 slots, slot ^= (row&7)
  char* Bbuf = lds + 16384;    // 2 x bf16 [128][64], same swizzle (double-buffered)
  const int tid  = threadIdx.x;
  const int lane = tid & 63;
  const int w    = tid >> 6;
  const int wr   = w >> 1, wc = w & 1;
  const int L    = blockIdx.x;                 // 0..511
  const int bx   = (L >> 3) & 7;               // n-block (inner per XCD)
  const int by   = ((L >> 6) << 3) | (L & 7);  // m-block (clustered per XCD)
  const int m0   = by * 128;
  const int n0   = bx * 128;
  const int lx   = lane & 15, lg = lane >> 4;

  f32x4 acc[4][4];
#pragma unroll
  for (int i = 0; i < 4; ++i)
#pragma unroll
    for (int j = 0; j < 4; ++j) acc[i][j] = 0.f;

  // per-thread staging task: 2 rows x full 64-k per 256-thread pass
  f32x4  t0[4], t1[4];   // MODE 0/1 A fp32 regs
  bf16x8 ta[4];          // MODE 2 A bf16 regs

  auto stageB = [&](int kt, char* dst) {
    const int k0 = kt * 64;
#pragma unroll
    for (int i = 0; i < 4; ++i) {
      int task = i * 256 + tid;
      int row = task >> 3, sl = task & 7;
      int sg = sl ^ (row & 7);
      gload16(Bw + (size_t)(n0 + row) * 1024 + k0 + sg * 8,
              dst + (i * 256 + w * 64) * 16);
    }
  };
  auto loadA = [&](int kt) {
    const int k0 = kt * 64;
    if constexpr (MODE == 2) {
      const short* Ab = (const short*)Aptr;
#pragma unroll
      for (int i = 0; i < 4; ++i) {
        int task = i * 256 + tid;
        int row = task >> 3, sl = task & 7;
        ta[i] = *(const bf16x8*)(Ab + (size_t)(m0 + row) * 1024 + k0 + sl * 8);
      }
    } else {
      const float* Af = (const float*)Aptr;
#pragma unroll
      for (int i = 0; i < 4; ++i) {
        int task = i * 256 + tid;
        int row = task >> 3, sl = task & 7;
        const float* src = Af + (size_t)(m0 + row) * 1024 + k0 + sl * 8;
        t0[i] = *(const f32x4*)src;
        t1[i] = *(const f32x4*)(src + 4);
      }
    }
  };
  auto writeA = [&]() {
#pragma unroll
    for (int i = 0; i < 4; ++i) {
      int task = i * 256 + tid;
      int row = task >> 3, sl = task & 7;
      char* dst = AsB + row * 128 + ((sl ^ (row & 7)) * 16);
      if constexpr (MODE == 2) {
        *(bf16x8*)dst = ta[i];
      } else {
        u32x4 u;
        u[0] = cvtpk(t0[i][0], t0[i][1]);
        u[1] = cvtpk(t0[i][2], t0[i][3]);
        u[2] = cvtpk(t1[i][0], t1[i][1]);
        u[3] = cvtpk(t1[i][2], t1[i][3]);
        *(u32x4*)dst = u;
      }
    }
  };

  // prologue: tile 0
  stageB(0, Bbuf);
  loadA(0);
  writeA();
  __syncthreads();

  for (int kt = 0; kt < 16; ++kt) {
    if (kt < 15) {
      stageB(kt + 1, Bbuf + ((kt + 1) & 1) * 16384);   // async, lands by barrier
      loadA(kt + 1);                                    // global->reg, hides under compute
    }
    const char* Bc = Bbuf + (kt & 1) * 16384;
#pragma unroll
    for (int ks = 0; ks < 2; ++ks) {
      bf16x8 av[4], bv[4];
#pragma unroll
      for (int mf = 0; mf < 4; ++mf) {
        int ar = wr * 64 + mf * 16 + lx;
        int sl = (ks * 4 + lg) ^ (ar & 7);
        av[mf] = *(const bf16x8*)(AsB + ar * 128 + sl * 16);
      }
#pragma unroll
      for (int nf = 0; nf < 4; ++nf) {
        int br = wc * 64 + nf * 16 + lx;
        int sl = (ks * 4 + lg) ^ (br & 7);
        bv[nf] = *(const bf16x8*)(Bc + br * 128 + sl * 16);
      }
#pragma unroll
      for (int mf = 0; mf < 4; ++mf)
#pragma unroll
        for (int nf = 0; nf < 4; ++nf)
          acc[mf][nf] = __builtin_amdgcn_mfma_f32_16x16x32_bf16(av[mf], bv[nf], acc[mf][nf], 0, 0, 0);
    }
    __syncthreads();     // readers done with AsB + B(t+1) gloads drained
    if (kt < 15) {
      writeA();          // overwrite AsB for t+1
      __syncthreads();   // A visible to all waves
    }
  }

  if constexpr (MODE == 0 || MODE == 2) {
#pragma unroll
    for (int mf = 0; mf < 4; ++mf)
#pragma unroll
      for (int nf = 0; nf < 4; ++nf) {
        int gn = n0 + wc * 64 + nf * 16 + lx;
        float bvl = bias[gn];
#pragma unroll
        for (int r = 0; r < 4; ++r) {
          int gm = m0 + wr * 64 + mf * 16 + lg * 4 + r;
          float val = (acc[mf][nf][r] + bvl) * scl;
          if constexpr (MODE == 0) {
            int bb = gm >> 11, s = gm & 2047, h = gn >> 6, dk = gn & 63;
            ((short*)Cout)[((size_t)(bb * 16 + h) << 17) + ((size_t)s << 6) + dk] = f2bf(val);
          } else {
            ((float*)Cout)[((size_t)gm << 10) + gn] = val;
          }
        }
      }
  } else {
    // MODE 1: transpose quadrant via per-wave LDS region, store coalesced [B,H,dk,S]
    short* wl = (short*)(void*)lds + w * 4096;  // [64 n][64 m]
#pragma unroll
    for (int mf = 0; mf < 4; ++mf)
#pragma unroll
      for (int nf = 0; nf < 4; ++nf) {
        int nl = nf * 16 + lx;
        float bvl = bias[n0 + wc * 64 + nl];
#pragma unroll
        for (int r = 0; r < 4; ++r) {
          int ml = mf * 16 + lg * 4 + r;
          wl[nl * 64 + ml] = f2bf((acc[mf][nf][r] + bvl) * scl);
        }
      }
    short* Cs = (short*)Cout;
#pragma unroll
    for (int p = 0; p < 8; ++p) {
      int d  = p * 8 + (lane >> 3);
      int mm = (lane & 7) * 8;
      bf16x4 lo = *(const bf16x4*)(wl + d * 64 + mm);
      bf16x4 hi = *(const bf16x4*)(wl + d * 64 + mm + 4);
      int gn = n0 + wc * 64 + d;
      int h = gn >> 6, dk = gn & 63;
      int gm = m0 + wr * 64 + mm;
      int bb = gm >> 11, s = gm & 2047;
      short8 val = { lo[0], lo[1], lo[2], lo[3], hi[0], hi[1], hi[2], hi[3] };
      *(short8*)(Cs + ((size_t)(bb * 16 + h) << 17) + ((size_t)dk << 11) + s) = val;
    }
  }
}

// ---------------- flash attention ----------------
// 1-D grid 1024, XCD-swizzled: the 16 q-tile blocks sharing one bh's K/V panel
// cluster on one XCD (panel = 512 KB, fits 4 MiB L2).
// Q pre-scaled by log2(e)/sqrt(dk) at projection -> scores already in exp2 domain.
__launch_bounds__(256, 3)
__global__ void attn_k(const short* __restrict__ Qb, const short* __restrict__ Kb,
                       const short* __restrict__ Vtb, short* __restrict__ Xb)
{
  __shared__ __align__(16) char lds[49152];
  char* Pb = lds + 32768;      // [128 q][64 kv] bf16, slot ^= (row&7)
  const int tid = threadIdx.x, lane = tid & 63, w = tid >> 6;
  const int lx = lane & 15, lg = lane >> 4;
  const int L  = blockIdx.x;                  // 0..1023
  const int q0 = ((L >> 3) & 15) * 128;
  const int bh = ((L >> 7) << 3) | (L & 7);
  const size_t base = (size_t)bh << 17;       // *131072

  bf16x8 aq[2][2];
#pragma unroll
  for (int m = 0; m < 2; ++m)
#pragma unroll
    for (int ks = 0; ks < 2; ++ks)
      aq[m][ks] = *(const bf16x8*)(Qb + base + (size_t)(q0 + w * 32 + m * 16 + lx) * 64 + ks * 32 + lg * 8);

  f32x4 o[2][4];
  f32x4 lrun[2];
  float mrun = -1e30f;
#pragma unroll
  for (int m = 0; m < 2; ++m) {
#pragma unroll
    for (int df = 0; df < 4; ++df) o[m][df] = 0.f;
    lrun[m] = 0.f;
  }
  const bf16x8 vones = { 0x3F80, 0x3F80, 0x3F80, 0x3F80, 0x3F80, 0x3F80, 0x3F80, 0x3F80 };

  // prologue: stage tile 0 into buf 0
#pragma unroll
  for (int i = 0; i < 2; ++i) {
    int task = i * 256 + tid;
    int row = task >> 3, sl = task & 7, sg = sl ^ (row & 7);
    gload16(Kb + base + (size_t)row * 64 + sg * 8, lds + (i * 256 + w * 64) * 16);
    gload16(Vtb + base + (size_t)row * 2048 + sg * 8, lds + 16384 + (i * 256 + w * 64) * 16);
  }
  __syncthreads();

  for (int kt = 0; kt < 32; ++kt) {
    char* Kcur = lds + (kt & 1) * 8192;
    char* Vcur = lds + 16384 + (kt & 1) * 8192;
    if (kt < 31) {
      const int kv1 = (kt + 1) * 64;
      char* Knxt = lds + ((kt + 1) & 1) * 8192;
      char* Vnxt = lds + 16384 + ((kt + 1) & 1) * 8192;
#pragma unroll
      for (int i = 0; i < 2; ++i) {
        int task = i * 256 + tid;
        int row = task >> 3, sl = task & 7, sg = sl ^ (row & 7);
        gload16(Kb + base + (size_t)(kv1 + row) * 64 + sg * 8, Knxt + (i * 256 + w * 64) * 16);
        gload16(Vtb + base + (size_t)row * 2048 + kv1 + sg * 8, Vnxt + (i * 256 + w * 64) * 16);
      }
    }

    // S = Q K^T (already in exp2 domain; Q pre-scaled)
    f32x4 sc[2][4];
#pragma unroll
    for (int m = 0; m < 2; ++m)
#pragma unroll
      for (int nf = 0; nf < 4; ++nf) sc[m][nf] = 0.f;
    __builtin_amdgcn_s_setprio(1);
#pragma unroll
    for (int ks = 0; ks < 2; ++ks) {
      bf16x8 bk[4];
#pragma unroll
      for (int nf = 0; nf < 4; ++nf) {
        int kr = nf * 16 + lx;
        int sl = (ks * 4 + lg) ^ (kr & 7);
        bk[nf] = *(const bf16x8*)(Kcur + kr * 128 + sl * 16);
      }
#pragma unroll
      for (int m = 0; m < 2; ++m)
#pragma unroll
        for (int nf = 0; nf < 4; ++nf)
          sc[m][nf] = __builtin_amdgcn_mfma_f32_16x16x32_bf16(aq[m][ks], bk[nf], sc[m][nf], 0, 0, 0);
    }
    __builtin_amdgcn_s_setprio(0);

    // wave-global tile max (upper-bounds every row max in this wave)
    f32x4 v0 = vmax4(sc[0][0], sc[0][1]);
    f32x4 v1 = vmax4(sc[0][2], sc[0][3]);
    f32x4 v2 = vmax4(sc[1][0], sc[1][1]);
    f32x4 v3 = vmax4(sc[1][2], sc[1][3]);
    v0 = vmax4(vmax4(v0, v1), vmax4(v2, v3));
    float mx = fmaxf(fmaxf(v0[0], v0[1]), fmaxf(v0[2], v0[3]));
    mx = fmaxf(mx, __shfl_xor(mx, 1));
    mx = fmaxf(mx, __shfl_xor(mx, 2));
    mx = fmaxf(mx, __shfl_xor(mx, 4));
    mx = fmaxf(mx, __shfl_xor(mx, 8));
    mx = fmaxf(mx, __shfl_xor(mx, 16));
    mx = fmaxf(mx, __shfl_xor(mx, 32));
    const float mn = fmaxf(mrun, mx);
    const float al = EXP2F(mrun - mn);
    mrun = mn;
    if (al < 1.0f) {   // wave-uniform: rescale only when max grew
#pragma unroll
      for (int m = 0; m < 2; ++m) {
#pragma unroll
        for (int df = 0; df < 4; ++df) o[m][df] *= al;
        lrun[m] *= al;
      }
    }
    const float nm = -mn;

    // P = exp2(S - mn) -> bf16 (cvt_pk) -> Plds (XOR-swizzled rows, wave-private)
#pragma unroll
    for (int m = 0; m < 2; ++m)
#pragma unroll
      for (int nf = 0; nf < 4; ++nf) {
        f32x4 p;
#pragma unroll
        for (int r = 0; r < 4; ++r) p[r] = EXP2F(sc[m][nf][r] + nm);
        uint32_t ab = cvtpk(p[0], p[1]);
        uint32_t cd = cvtpk(p[2], p[3]);
        short v4[4] = { (short)ab, (short)(ab >> 16), (short)cd, (short)(cd >> 16) };
#pragma unroll
        for (int r = 0; r < 4; ++r) {
          int row = w * 32 + m * 16 + lg * 4 + r;
          int slot = (nf * 2 + (lx >> 3)) ^ (row & 7);
          *(short*)(Pb + row * 128 + slot * 16 + (lx & 7) * 2) = v4[r];
        }
      }

    // O += P V ; row-sums via all-ones B fragment
    f32x4 rs0 = 0.f, rs1 = 0.f;
#pragma unroll
    for (int ks = 0; ks < 2; ++ks) {
      bf16x8 pa[2], bvv[4];
#pragma unroll
      for (int m = 0; m < 2; ++m) {
        int row = w * 32 + m * 16 + lx;
        int sl = (ks * 4 + lg) ^ (row & 7);
        pa[m] = *(const bf16x8*)(Pb + row * 128 + sl * 16);
      }
#pragma unroll
      for (int df = 0; df < 4; ++df) {
        int dr = df * 16 + lx;
        int sl = (ks * 4 + lg) ^ (dr & 7);
        bvv[df] = *(const bf16x8*)(Vcur + dr * 128 + sl * 16);
      }
      __builtin_amdgcn_s_setprio(1);
      rs0 = __builtin_amdgcn_mfma_f32_16x16x32_bf16(pa[0], vones, rs0, 0, 0, 0);
      rs1 = __builtin_amdgcn_mfma_f32_16x16x32_bf16(pa[1], vones, rs1, 0, 0, 0);
#pragma unroll
      for (int m = 0; m < 2; ++m)
#pragma unroll
        for (int df = 0; df < 4; ++df)
          o[m][df] = __builtin_amdgcn_mfma_f32_16x16x32_bf16(pa[m], bvv[df], o[m][df], 0, 0, 0);
      __builtin_amdgcn_s_setprio(0);
    }
    lrun[0] += rs0;
    lrun[1] += rs1;

    __syncthreads();   // staged next tile complete + all waves done with cur bufs
  }

  // epilogue: O / l  -> X [B,S,1024] bf16 (merged heads)
  const int bb = bh >> 4, h = bh & 15;
#pragma unroll
  for (int m = 0; m < 2; ++m)
#pragma unroll
    for (int r = 0; r < 4; ++r) {
      float inv = 1.0f / lrun[m][r];
      int gs = q0 + w * 32 + m * 16 + lg * 4 + r;
      size_t rowb = ((size_t)(bb * 2048 + gs)) << 10;
#pragma unroll
      for (int df = 0; df < 4; ++df)
        Xb[rowb + h * 64 + df * 16 + lx] = f2bf(o[m][df][r] * inv);
    }
}

// ---------------- host ----------------
extern "C" void kernel_launch(void* const* d_in, const int* in_sizes, int n_in,
                              void* d_out, int out_size, void* d_ws, size_t ws_size,
                              hipStream_t stream)
{
  (void)in_sizes; (void)n_in; (void)out_size; (void)ws_size;
  const float* q  = (const float*)d_in[0];
  const float* k  = (const float*)d_in[1];
  const float* v  = (const float*)d_in[2];
  const float* Wq = (const float*)d_in[3];
  const float* bq = (const float*)d_in[4];
  const float* Wk = (const float*)d_in[5];
  const float* bk = (const float*)d_in[6];
  const float* Wv = (const float*)d_in[7];
  const float* bv = (const float*)d_in[8];
  const float* Wo = (const float*)d_in[9];
  const float* bo = (const float*)d_in[10];

  short* ws  = (short*)d_ws;
  short* wqb = ws;                  // 1024*1024 each
  short* wkb = wqb + 1048576;
  short* wvb = wkb + 1048576;
  short* wob = wvb + 1048576;
  short* Qb  = wob + 1048576;       // 8192*1024 each
  short* Kb  = Qb  + 8388608;
  short* Vtb = Kb  + 8388608;
  short* Xb  = Vtb + 8388608;       // total 75,497,472 bytes

  const float QSCALE = 0.18033688011112042f;  // log2(e)/sqrt(64)

  cvtw_k<<<dim3(1024, 4), 256, 0, stream>>>(Wq, Wk, Wv, Wo, wqb);
  gemm_k<0><<<512, 256, 0, stream>>>(q, wqb, bq, Qb, QSCALE);
  gemm_k<0><<<512, 256, 0, stream>>>(k, wkb, bk, Kb, 1.0f);
  gemm_k<1><<<512, 256, 0, stream>>>(v, wvb, bv, Vtb, 1.0f);
  attn_k<<<1024, 256, 0, stream>>>(Qb, Kb, Vtb, Xb);
  gemm_k<2><<<512, 256, 0, stream>>>(Xb, wob, bo, d_out, 1.0f);
}

// Round 8
// 238.616 us; speedup vs baseline: 1.5500x; 1.0607x over previous
//
#include <hip/hip_runtime.h>
#include <hip/hip_bf16.h>
#include <stdint.h>

#define DEV static __device__ __forceinline__

typedef float    f32x4  __attribute__((ext_vector_type(4)));
typedef short    bf16x8 __attribute__((ext_vector_type(8)));
typedef short    bf16x4 __attribute__((ext_vector_type(4)));
typedef short    short8 __attribute__((ext_vector_type(8)));
typedef uint32_t u32x4  __attribute__((ext_vector_type(4)));

#if __has_builtin(__builtin_amdgcn_exp2f)
#define EXP2F(x) __builtin_amdgcn_exp2f(x)
#else
#define EXP2F(x) exp2f(x)
#endif

// fp32 -> bf16 bits, round-to-nearest-even (epilogue-only; hot paths use cvt_pk)
DEV short f2bf(float f) {
  union { float f; uint32_t u; } v; v.f = f;
  uint32_t u = v.u;
  u = (u + 0x7FFFu + ((u >> 16) & 1u)) >> 16;
  return (short)u;
}

// two f32 -> packed 2x bf16 (RNE), single instruction
DEV uint32_t cvtpk(float lo, float hi) {
  uint32_t r;
  asm("v_cvt_pk_bf16_f32 %0, %1, %2" : "=v"(r) : "v"(lo), "v"(hi));
  return r;
}

DEV f32x4 vmax4(f32x4 a, f32x4 b) {
  f32x4 r;
  r[0] = fmaxf(a[0], b[0]); r[1] = fmaxf(a[1], b[1]);
  r[2] = fmaxf(a[2], b[2]); r[3] = fmaxf(a[3], b[3]);
  return r;
}

// async global->LDS, 16B per lane; LDS dest = wave-uniform base + lane*16
DEV void gload16(const void* g, void* l) {
  __builtin_amdgcn_global_load_lds((const __attribute__((address_space(1))) void*)g,
                                   (__attribute__((address_space(3))) void*)l,
                                   16, 0, 0);
}

// ---------------- weight fp32 -> bf16 ----------------
__global__ void cvtw_k(const float* __restrict__ w0, const float* __restrict__ w1,
                       const float* __restrict__ w2, const float* __restrict__ w3,
                       short* __restrict__ outp)
{
  const int which = blockIdx.y;
  const float* src = which == 0 ? w0 : which == 1 ? w1 : which == 2 ? w2 : w3;
  const int idx = (blockIdx.x * 256 + threadIdx.x) * 4;
  f32x4 v = *(const f32x4*)(src + idx);
  bf16x4 o;
#pragma unroll
  for (int j = 0; j < 4; ++j) o[j] = f2bf(v[j]);
  *(bf16x4*)(outp + (size_t)which * 1048576 + idx) = o;
}

// ---------------- GEMM body: C[m][n] = (sum_k A[m][k]*B[n][k] + bias[n]) * scl --------
// M=8192, N=1024, K=1024. Tile 128x128, BK=64, 4 waves (2x2), 16x16x32 bf16 MFMA.
// 2-phase pipeline; L is the XCD-swizzled block id in [0,512).
// MODE 0: A fp32, C bf16 -> [B,H,S,dk]
// MODE 1: A fp32, C bf16 -> [B,H,dk,S]  (transposed via LDS bounce)
// MODE 2: A bf16, C fp32 -> [M][N]
template<int MODE>
DEV void gemm_body(char* lds, const void* Aptr, const short* Bw,
                   const float* bias, void* Cout, float scl, int L)
{
  char* AsB  = lds;            // bf16 [128][64], row=128B=8 slots, slot ^= (row&7)
  char* Bbuf = lds + 16384;    // 2 x bf16 [128][64], same swizzle (double-buffered)
  const int tid  = threadIdx.x;
  const int lane = tid & 63;
  const int w    = tid >> 6;
  const int wr   = w >> 1, wc = w & 1;
  const int bx   = (L >> 3) & 7;               // n-block (inner per XCD)
  const int by   = ((L >> 6) << 3) | (L & 7);  // m-block (clustered per XCD)
  const int m0   = by * 128;
  const int n0   = bx * 128;
  const int lx   = lane & 15, lg = lane >> 4;

  f32x4 acc[4][4];
#pragma unroll
  for (int i = 0; i < 4; ++i)
#pragma unroll
    for (int j = 0; j < 4; ++j) acc[i][j] = 0.f;

  f32x4  t0[4], t1[4];   // MODE 0/1 A fp32 regs
  bf16x8 ta[4];          // MODE 2 A bf16 regs

  auto stageB = [&](int kt, char* dst) {
    const int k0 = kt * 64;
#pragma unroll
    for (int i = 0; i < 4; ++i) {
      int task = i * 256 + tid;
      int row = task >> 3, sl = task & 7;
      int sg = sl ^ (row & 7);
      gload16(Bw + (size_t)(n0 + row) * 1024 + k0 + sg * 8,
              dst + (i * 256 + w * 64) * 16);
    }
  };
  auto loadA = [&](int kt) {
    const int k0 = kt * 64;
    if constexpr (MODE == 2) {
      const short* Ab = (const short*)Aptr;
#pragma unroll
      for (int i = 0; i < 4; ++i) {
        int task = i * 256 + tid;
        int row = task >> 3, sl = task & 7;
        ta[i] = *(const bf16x8*)(Ab + (size_t)(m0 + row) * 1024 + k0 + sl * 8);
      }
    } else {
      const float* Af = (const float*)Aptr;
#pragma unroll
      for (int i = 0; i < 4; ++i) {
        int task = i * 256 + tid;
        int row = task >> 3, sl = task & 7;
        const float* src = Af + (size_t)(m0 + row) * 1024 + k0 + sl * 8;
        t0[i] = *(const f32x4*)src;
        t1[i] = *(const f32x4*)(src + 4);
      }
    }
  };
  auto writeA = [&]() {
#pragma unroll
    for (int i = 0; i < 4; ++i) {
      int task = i * 256 + tid;
      int row = task >> 3, sl = task & 7;
      char* dst = AsB + row * 128 + ((sl ^ (row & 7)) * 16);
      if constexpr (MODE == 2) {
        *(bf16x8*)dst = ta[i];
      } else {
        u32x4 u;
        u[0] = cvtpk(t0[i][0], t0[i][1]);
        u[1] = cvtpk(t0[i][2], t0[i][3]);
        u[2] = cvtpk(t1[i][0], t1[i][1]);
        u[3] = cvtpk(t1[i][2], t1[i][3]);
        *(u32x4*)dst = u;
      }
    }
  };

  // prologue: tile 0
  stageB(0, Bbuf);
  loadA(0);
  writeA();
  __syncthreads();

  for (int kt = 0; kt < 16; ++kt) {
    if (kt < 15) {
      stageB(kt + 1, Bbuf + ((kt + 1) & 1) * 16384);   // async, lands by barrier
      loadA(kt + 1);                                    // global->reg, hides under compute
    }
    const char* Bc = Bbuf + (kt & 1) * 16384;
#pragma unroll
    for (int ks = 0; ks < 2; ++ks) {
      bf16x8 av[4], bv[4];
#pragma unroll
      for (int mf = 0; mf < 4; ++mf) {
        int ar = wr * 64 + mf * 16 + lx;
        int sl = (ks * 4 + lg) ^ (ar & 7);
        av[mf] = *(const bf16x8*)(AsB + ar * 128 + sl * 16);
      }
#pragma unroll
      for (int nf = 0; nf < 4; ++nf) {
        int br = wc * 64 + nf * 16 + lx;
        int sl = (ks * 4 + lg) ^ (br & 7);
        bv[nf] = *(const bf16x8*)(Bc + br * 128 + sl * 16);
      }
#pragma unroll
      for (int mf = 0; mf < 4; ++mf)
#pragma unroll
        for (int nf = 0; nf < 4; ++nf)
          acc[mf][nf] = __builtin_amdgcn_mfma_f32_16x16x32_bf16(av[mf], bv[nf], acc[mf][nf], 0, 0, 0);
    }
    __syncthreads();     // readers done with AsB + B(t+1) gloads drained
    if (kt < 15) {
      writeA();          // overwrite AsB for t+1
      __syncthreads();   // A visible to all waves
    }
  }

  if constexpr (MODE == 0 || MODE == 2) {
#pragma unroll
    for (int mf = 0; mf < 4; ++mf)
#pragma unroll
      for (int nf = 0; nf < 4; ++nf) {
        int gn = n0 + wc * 64 + nf * 16 + lx;
        float bvl = bias[gn];
#pragma unroll
        for (int r = 0; r < 4; ++r) {
          int gm = m0 + wr * 64 + mf * 16 + lg * 4 + r;
          float val = (acc[mf][nf][r] + bvl) * scl;
          if constexpr (MODE == 0) {
            int bb = gm >> 11, s = gm & 2047, h = gn >> 6, dk = gn & 63;
            ((short*)Cout)[((size_t)(bb * 16 + h) << 17) + ((size_t)s << 6) + dk] = f2bf(val);
          } else {
            ((float*)Cout)[((size_t)gm << 10) + gn] = val;
          }
        }
      }
  } else {
    // MODE 1: transpose quadrant via per-wave LDS region, store coalesced [B,H,dk,S]
    short* wl = (short*)(void*)lds + w * 4096;  // [64 n][64 m]
#pragma unroll
    for (int mf = 0; mf < 4; ++mf)
#pragma unroll
      for (int nf = 0; nf < 4; ++nf) {
        int nl = nf * 16 + lx;
        float bvl = bias[n0 + wc * 64 + nl];
#pragma unroll
        for (int r = 0; r < 4; ++r) {
          int ml = mf * 16 + lg * 4 + r;
          wl[nl * 64 + ml] = f2bf((acc[mf][nf][r] + bvl) * scl);
        }
      }
    short* Cs = (short*)Cout;
#pragma unroll
    for (int p = 0; p < 8; ++p) {
      int d  = p * 8 + (lane >> 3);
      int mm = (lane & 7) * 8;
      bf16x4 lo = *(const bf16x4*)(wl + d * 64 + mm);
      bf16x4 hi = *(const bf16x4*)(wl + d * 64 + mm + 4);
      int gn = n0 + wc * 64 + d;
      int h = gn >> 6, dk = gn & 63;
      int gm = m0 + wr * 64 + mm;
      int bb = gm >> 11, s = gm & 2047;
      short8 val = { lo[0], lo[1], lo[2], lo[3], hi[0], hi[1], hi[2], hi[3] };
      *(short8*)(Cs + ((size_t)(bb * 16 + h) << 17) + ((size_t)dk << 11) + s) = val;
    }
  }
}

// fused Q/K/V projections: blocks [0,512) Q, [512,1024) K, [1024,1536) V
__launch_bounds__(256, 3)
__global__ void proj_k(const float* __restrict__ qA, const float* __restrict__ kA,
                       const float* __restrict__ vA,
                       const short* __restrict__ wq, const short* __restrict__ wk,
                       const short* __restrict__ wv,
                       const float* __restrict__ bq, const float* __restrict__ bk,
                       const float* __restrict__ bv,
                       short* __restrict__ Qb, short* __restrict__ Kb,
                       short* __restrict__ Vtb, float qs)
{
  __shared__ __align__(16) char lds[49152];
  const int gid = blockIdx.x;
  const int which = gid >> 9, L = gid & 511;
  if (which == 0)      gemm_body<0>(lds, qA, wq, bq, Qb, qs, L);
  else if (which == 1) gemm_body<0>(lds, kA, wk, bk, Kb, 1.0f, L);
  else                 gemm_body<1>(lds, vA, wv, bv, Vtb, 1.0f, L);
}

__launch_bounds__(256, 3)
__global__ void outproj_k(const short* __restrict__ Xb, const short* __restrict__ wo,
                          const float* __restrict__ bo, void* __restrict__ out)
{
  __shared__ __align__(16) char lds[49152];
  gemm_body<2>(lds, Xb, wo, bo, out, 1.0f, blockIdx.x);
}

// ---------------- flash attention (round-3 verified structure) ----------------
// 1-D grid 1024, XCD-swizzled: the 16 q-tile blocks sharing one bh's K/V panel
// cluster on one XCD. 4 waves x 32 q-rows = 128 rows/block.
// Q pre-scaled by log2(e)/sqrt(dk) at projection -> scores already in exp2 domain.
__launch_bounds__(256, 3)
__global__ void attn_k(const short* __restrict__ Qb, const short* __restrict__ Kb,
                       const short* __restrict__ Vtb, short* __restrict__ Xb)
{
  __shared__ __align__(16) char lds[49152];
  char* Pb = lds + 32768;      // [128 q][64 kv] bf16, slot ^= (row&7)
  const int tid = threadIdx.x, lane = tid & 63, w = tid >> 6;
  const int lx = lane & 15, lg = lane >> 4;
  const int L  = blockIdx.x;                  // 0..1023
  const int q0 = ((L >> 3) & 15) * 128;
  const int bh = ((L >> 7) << 3) | (L & 7);
  const size_t base = (size_t)bh << 17;       // *131072

  bf16x8 aq[2][2];
#pragma unroll
  for (int m = 0; m < 2; ++m)
#pragma unroll
    for (int ks = 0; ks < 2; ++ks)
      aq[m][ks] = *(const bf16x8*)(Qb + base + (size_t)(q0 + w * 32 + m * 16 + lx) * 64 + ks * 32 + lg * 8);

  f32x4 o[2][4];
  f32x4 lrun[2];
  float mrun = -1e30f;
#pragma unroll
  for (int m = 0; m < 2; ++m) {
#pragma unroll
    for (int df = 0; df < 4; ++df) o[m][df] = 0.f;
    lrun[m] = 0.f;
  }
  const bf16x8 vones = { 0x3F80, 0x3F80, 0x3F80, 0x3F80, 0x3F80, 0x3F80, 0x3F80, 0x3F80 };

  // prologue: stage tile 0 into buf 0
#pragma unroll
  for (int i = 0; i < 2; ++i) {
    int task = i * 256 + tid;
    int row = task >> 3, sl = task & 7, sg = sl ^ (row & 7);
    gload16(Kb + base + (size_t)row * 64 + sg * 8, lds + (i * 256 + w * 64) * 16);
    gload16(Vtb + base + (size_t)row * 2048 + sg * 8, lds + 16384 + (i * 256 + w * 64) * 16);
  }
  __syncthreads();

  for (int kt = 0; kt < 32; ++kt) {
    char* Kcur = lds + (kt & 1) * 8192;
    char* Vcur = lds + 16384 + (kt & 1) * 8192;
    if (kt < 31) {
      const int kv1 = (kt + 1) * 64;
      char* Knxt = lds + ((kt + 1) & 1) * 8192;
      char* Vnxt = lds + 16384 + ((kt + 1) & 1) * 8192;
#pragma unroll
      for (int i = 0; i < 2; ++i) {
        int task = i * 256 + tid;
        int row = task >> 3, sl = task & 7, sg = sl ^ (row & 7);
        gload16(Kb + base + (size_t)(kv1 + row) * 64 + sg * 8, Knxt + (i * 256 + w * 64) * 16);
        gload16(Vtb + base + (size_t)row * 2048 + kv1 + sg * 8, Vnxt + (i * 256 + w * 64) * 16);
      }
    }

    // S = Q K^T (already in exp2 domain; Q pre-scaled)
    f32x4 sc[2][4];
#pragma unroll
    for (int m = 0; m < 2; ++m)
#pragma unroll
      for (int nf = 0; nf < 4; ++nf) sc[m][nf] = 0.f;
    __builtin_amdgcn_s_setprio(1);
#pragma unroll
    for (int ks = 0; ks < 2; ++ks) {
      bf16x8 bk[4];
#pragma unroll
      for (int nf = 0; nf < 4; ++nf) {
        int kr = nf * 16 + lx;
        int sl = (ks * 4 + lg) ^ (kr & 7);
        bk[nf] = *(const bf16x8*)(Kcur + kr * 128 + sl * 16);
      }
#pragma unroll
      for (int m = 0; m < 2; ++m)
#pragma unroll
        for (int nf = 0; nf < 4; ++nf)
          sc[m][nf] = __builtin_amdgcn_mfma_f32_16x16x32_bf16(aq[m][ks], bk[nf], sc[m][nf], 0, 0, 0);
    }
    __builtin_amdgcn_s_setprio(0);

    // wave-global tile max (upper-bounds every row max in this wave)
    f32x4 v0 = vmax4(sc[0][0], sc[0][1]);
    f32x4 v1 = vmax4(sc[0][2], sc[0][3]);
    f32x4 v2 = vmax4(sc[1][0], sc[1][1]);
    f32x4 v3 = vmax4(sc[1][2], sc[1][3]);
    v0 = vmax4(vmax4(v0, v1), vmax4(v2, v3));
    float mx = fmaxf(fmaxf(v0[0], v0[1]), fmaxf(v0[2], v0[3]));
    mx = fmaxf(mx, __shfl_xor(mx, 1));
    mx = fmaxf(mx, __shfl_xor(mx, 2));
    mx = fmaxf(mx, __shfl_xor(mx, 4));
    mx = fmaxf(mx, __shfl_xor(mx, 8));
    mx = fmaxf(mx, __shfl_xor(mx, 16));
    mx = fmaxf(mx, __shfl_xor(mx, 32));
    const float mn = fmaxf(mrun, mx);
    const float al = EXP2F(mrun - mn);
    mrun = mn;
    if (al < 1.0f) {   // wave-uniform: rescale only when max grew
#pragma unroll
      for (int m = 0; m < 2; ++m) {
#pragma unroll
        for (int df = 0; df < 4; ++df) o[m][df] *= al;
        lrun[m] *= al;
      }
    }
    const float nm = -mn;

    // P = exp2(S - mn) -> bf16 (cvt_pk) -> Plds (XOR-swizzled rows, wave-private)
#pragma unroll
    for (int m = 0; m < 2; ++m)
#pragma unroll
      for (int nf = 0; nf < 4; ++nf) {
        f32x4 p;
#pragma unroll
        for (int r = 0; r < 4; ++r) p[r] = EXP2F(sc[m][nf][r] + nm);
        uint32_t ab = cvtpk(p[0], p[1]);
        uint32_t cd = cvtpk(p[2], p[3]);
        short v4[4] = { (short)ab, (short)(ab >> 16), (short)cd, (short)(cd >> 16) };
#pragma unroll
        for (int r = 0; r < 4; ++r) {
          int row = w * 32 + m * 16 + lg * 4 + r;
          int slot = (nf * 2 + (lx >> 3)) ^ (row & 7);
          *(short*)(Pb + row * 128 + slot * 16 + (lx & 7) * 2) = v4[r];
        }
      }

    // O += P V ; row-sums via all-ones B fragment
    f32x4 rs0 = 0.f, rs1 = 0.f;
#pragma unroll
    for (int ks = 0; ks < 2; ++ks) {
      bf16x8 pa[2], bvv[4];
#pragma unroll
      for (int m = 0; m < 2; ++m) {
        int row = w * 32 + m * 16 + lx;
        int sl = (ks * 4 + lg) ^ (row & 7);
        pa[m] = *(const bf16x8*)(Pb + row * 128 + sl * 16);
      }
#pragma unroll
      for (int df = 0; df < 4; ++df) {
        int dr = df * 16 + lx;
        int sl = (ks * 4 + lg) ^ (dr & 7);
        bvv[df] = *(const bf16x8*)(Vcur + dr * 128 + sl * 16);
      }
      __builtin_amdgcn_s_setprio(1);
      rs0 = __builtin_amdgcn_mfma_f32_16x16x32_bf16(pa[0], vones, rs0, 0, 0, 0);
      rs1 = __builtin_amdgcn_mfma_f32_16x16x32_bf16(pa[1], vones, rs1, 0, 0, 0);
#pragma unroll
      for (int m = 0; m < 2; ++m)
#pragma unroll
        for (int df = 0; df < 4; ++df)
          o[m][df] = __builtin_amdgcn_mfma_f32_16x16x32_bf16(pa[m], bvv[df], o[m][df], 0, 0, 0);
      __builtin_amdgcn_s_setprio(0);
    }
    lrun[0] += rs0;
    lrun[1] += rs1;

    __syncthreads();   // staged next tile complete + all waves done with cur bufs
  }

  // epilogue: O / l  -> X [B,S,1024] bf16 (merged heads)
  const int bb = bh >> 4, h = bh & 15;
#pragma unroll
  for (int m = 0; m < 2; ++m)
#pragma unroll
    for (int r = 0; r < 4; ++r) {
      float inv = 1.0f / lrun[m][r];
      int gs = q0 + w * 32 + m * 16 + lg * 4 + r;
      size_t rowb = ((size_t)(bb * 2048 + gs)) << 10;
#pragma unroll
      for (int df = 0; df < 4; ++df)
        Xb[rowb + h * 64 + df * 16 + lx] = f2bf(o[m][df][r] * inv);
    }
}

// ---------------- host ----------------
extern "C" void kernel_launch(void* const* d_in, const int* in_sizes, int n_in,
                              void* d_out, int out_size, void* d_ws, size_t ws_size,
                              hipStream_t stream)
{
  (void)in_sizes; (void)n_in; (void)out_size; (void)ws_size;
  const float* q  = (const float*)d_in[0];
  const float* k  = (const float*)d_in[1];
  const float* v  = (const float*)d_in[2];
  const float* Wq = (const float*)d_in[3];
  const float* bq = (const float*)d_in[4];
  const float* Wk = (const float*)d_in[5];
  const float* bk = (const float*)d_in[6];
  const float* Wv = (const float*)d_in[7];
  const float* bv = (const float*)d_in[8];
  const float* Wo = (const float*)d_in[9];
  const float* bo = (const float*)d_in[10];

  short* ws  = (short*)d_ws;
  short* wqb = ws;                  // 1024*1024 each
  short* wkb = wqb + 1048576;
  short* wvb = wkb + 1048576;
  short* wob = wvb + 1048576;
  short* Qb  = wob + 1048576;       // 8192*1024 each
  short* Kb  = Qb  + 8388608;
  short* Vtb = Kb  + 8388608;
  short* Xb  = Vtb + 8388608;       // total 75,497,472 bytes

  const float QSCALE = 0.18033688011112042f;  // log2(e)/sqrt(64)

  cvtw_k<<<dim3(1024, 4), 256, 0, stream>>>(Wq, Wk, Wv, Wo, wqb);
  proj_k<<<1536, 256, 0, stream>>>(q, k, v, wqb, wkb, wvb, bq, bk, bv,
                                   Qb, Kb, Vtb, QSCALE);
  attn_k<<<1024, 256, 0, stream>>>(Qb, Kb, Vtb, Xb);
  outproj_k<<<512, 256, 0, stream>>>(Xb, wob, bo, d_out);
}

// Round 12
// 237.471 us; speedup vs baseline: 1.5575x; 1.0048x over previous
//
#include <hip/hip_runtime.h>
#include <hip/hip_bf16.h>
#include <stdint.h>

#define DEV static __device__ __forceinline__

typedef float    f32x4  __attribute__((ext_vector_type(4)));
typedef short    bf16x8 __attribute__((ext_vector_type(8)));
typedef short    bf16x4 __attribute__((ext_vector_type(4)));
typedef short    short8 __attribute__((ext_vector_type(8)));
typedef uint32_t u32x4  __attribute__((ext_vector_type(4)));

#if __has_builtin(__builtin_amdgcn_exp2f)
#define EXP2F(x) __builtin_amdgcn_exp2f(x)
#else
#define EXP2F(x) exp2f(x)
#endif

// fp32 -> bf16 bits, round-to-nearest-even (epilogue-only; hot paths use cvt_pk)
DEV short f2bf(float f) {
  union { float f; uint32_t u; } v; v.f = f;
  uint32_t u = v.u;
  u = (u + 0x7FFFu + ((u >> 16) & 1u)) >> 16;
  return (short)u;
}

// two f32 -> packed 2x bf16 (RNE), single instruction
DEV uint32_t cvtpk(float lo, float hi) {
  uint32_t r;
  asm("v_cvt_pk_bf16_f32 %0, %1, %2" : "=v"(r) : "v"(lo), "v"(hi));
  return r;
}

DEV f32x4 vmax4(f32x4 a, f32x4 b) {
  f32x4 r;
  r[0] = fmaxf(a[0], b[0]); r[1] = fmaxf(a[1], b[1]);
  r[2] = fmaxf(a[2], b[2]); r[3] = fmaxf(a[3], b[3]);
  return r;
}

// async global->LDS, 16B per lane; LDS dest = wave-uniform base + lane*16
DEV void gload16(const void* g, void* l) {
  __builtin_amdgcn_global_load_lds((const __attribute__((address_space(1))) void*)g,
                                   (__attribute__((address_space(3))) void*)l,
                                   16, 0, 0);
}

// ---------------- weight fp32 -> bf16 ----------------
__global__ void cvtw_k(const float* __restrict__ w0, const float* __restrict__ w1,
                       const float* __restrict__ w2, const float* __restrict__ w3,
                       short* __restrict__ outp)
{
  const int which = blockIdx.y;
  const float* src = which == 0 ? w0 : which == 1 ? w1 : which == 2 ? w2 : w3;
  const int idx = (blockIdx.x * 256 + threadIdx.x) * 4;
  f32x4 v = *(const f32x4*)(src + idx);
  bf16x4 o;
#pragma unroll
  for (int j = 0; j < 4; ++j) o[j] = f2bf(v[j]);
  *(bf16x4*)(outp + (size_t)which * 1048576 + idx) = o;
}

// ---------------- GEMM body: C[m][n] = (sum_k A[m][k]*B[n][k] + bias[n]) * scl --------
// M=8192, N=1024, K=1024. Tile 128x128, BK=64, 4 waves (2x2), 16x16x32 bf16 MFMA.
// 2-phase pipeline; L is the XCD-swizzled block id in [0,512).
// MODE 0: A fp32, C bf16 -> [B,H,S,dk]
// MODE 1: A fp32, C bf16 -> [B,H,dk,S]  (transposed via LDS bounce)
// MODE 2: A bf16, C fp32 -> [M][N]
template<int MODE>
DEV void gemm_body(char* lds, const void* Aptr, const short* Bw,
                   const float* bias, void* Cout, float scl, int L)
{
  char* AsB  = lds;            // bf16 [128][64], row=128B=8 slots, slot ^= (row&7)
  char* Bbuf = lds + 16384;    // 2 x bf16 [128][64], same swizzle (double-buffered)
  const int tid  = threadIdx.x;
  const int lane = tid & 63;
  const int w    = tid >> 6;
  const int wr   = w >> 1, wc = w & 1;
  const int bx   = (L >> 3) & 7;               // n-block (inner per XCD)
  const int by   = ((L >> 6) << 3) | (L & 7);  // m-block (clustered per XCD)
  const int m0   = by * 128;
  const int n0   = bx * 128;
  const int lx   = lane & 15, lg = lane >> 4;

  f32x4 acc[4][4];
#pragma unroll
  for (int i = 0; i < 4; ++i)
#pragma unroll
    for (int j = 0; j < 4; ++j) acc[i][j] = 0.f;

  f32x4  t0[4], t1[4];   // MODE 0/1 A fp32 regs
  bf16x8 ta[4];          // MODE 2 A bf16 regs

  auto stageB = [&](int kt, char* dst) {
    const int k0 = kt * 64;
#pragma unroll
    for (int i = 0; i < 4; ++i) {
      int task = i * 256 + tid;
      int row = task >> 3, sl = task & 7;
      int sg = sl ^ (row & 7);
      gload16(Bw + (size_t)(n0 + row) * 1024 + k0 + sg * 8,
              dst + (i * 256 + w * 64) * 16);
    }
  };
  auto loadA = [&](int kt) {
    const int k0 = kt * 64;
    if constexpr (MODE == 2) {
      const short* Ab = (const short*)Aptr;
#pragma unroll
      for (int i = 0; i < 4; ++i) {
        int task = i * 256 + tid;
        int row = task >> 3, sl = task & 7;
        ta[i] = *(const bf16x8*)(Ab + (size_t)(m0 + row) * 1024 + k0 + sl * 8);
      }
    } else {
      const float* Af = (const float*)Aptr;
#pragma unroll
      for (int i = 0; i < 4; ++i) {
        int task = i * 256 + tid;
        int row = task >> 3, sl = task & 7;
        const float* src = Af + (size_t)(m0 + row) * 1024 + k0 + sl * 8;
        t0[i] = *(const f32x4*)src;
        t1[i] = *(const f32x4*)(src + 4);
      }
    }
  };
  auto writeA = [&]() {
#pragma unroll
    for (int i = 0; i < 4; ++i) {
      int task = i * 256 + tid;
      int row = task >> 3, sl = task & 7;
      char* dst = AsB + row * 128 + ((sl ^ (row & 7)) * 16);
      if constexpr (MODE == 2) {
        *(bf16x8*)dst = ta[i];
      } else {
        u32x4 u;
        u[0] = cvtpk(t0[i][0], t0[i][1]);
        u[1] = cvtpk(t0[i][2], t0[i][3]);
        u[2] = cvtpk(t1[i][0], t1[i][1]);
        u[3] = cvtpk(t1[i][2], t1[i][3]);
        *(u32x4*)dst = u;
      }
    }
  };

  // prologue: tile 0
  stageB(0, Bbuf);
  loadA(0);
  writeA();
  __syncthreads();

  for (int kt = 0; kt < 16; ++kt) {
    if (kt < 15) {
      stageB(kt + 1, Bbuf + ((kt + 1) & 1) * 16384);   // async, lands by barrier
      loadA(kt + 1);                                    // global->reg, hides under compute
    }
    const char* Bc = Bbuf + (kt & 1) * 16384;
#pragma unroll
    for (int ks = 0; ks < 2; ++ks) {
      bf16x8 av[4], bv[4];
#pragma unroll
      for (int mf = 0; mf < 4; ++mf) {
        int ar = wr * 64 + mf * 16 + lx;
        int sl = (ks * 4 + lg) ^ (ar & 7);
        av[mf] = *(const bf16x8*)(AsB + ar * 128 + sl * 16);
      }
#pragma unroll
      for (int nf = 0; nf < 4; ++nf) {
        int br = wc * 64 + nf * 16 + lx;
        int sl = (ks * 4 + lg) ^ (br & 7);
        bv[nf] = *(const bf16x8*)(Bc + br * 128 + sl * 16);
      }
#pragma unroll
      for (int mf = 0; mf < 4; ++mf)
#pragma unroll
        for (int nf = 0; nf < 4; ++nf)
          acc[mf][nf] = __builtin_amdgcn_mfma_f32_16x16x32_bf16(av[mf], bv[nf], acc[mf][nf], 0, 0, 0);
    }
    __syncthreads();     // readers done with AsB + B(t+1) gloads drained
    if (kt < 15) {
      writeA();          // overwrite AsB for t+1
      __syncthreads();   // A visible to all waves
    }
  }

  if constexpr (MODE == 0 || MODE == 2) {
#pragma unroll
    for (int mf = 0; mf < 4; ++mf)
#pragma unroll
      for (int nf = 0; nf < 4; ++nf) {
        int gn = n0 + wc * 64 + nf * 16 + lx;
        float bvl = bias[gn];
#pragma unroll
        for (int r = 0; r < 4; ++r) {
          int gm = m0 + wr * 64 + mf * 16 + lg * 4 + r;
          float val = (acc[mf][nf][r] + bvl) * scl;
          if constexpr (MODE == 0) {
            int bb = gm >> 11, s = gm & 2047, h = gn >> 6, dk = gn & 63;
            ((short*)Cout)[((size_t)(bb * 16 + h) << 17) + ((size_t)s << 6) + dk] = f2bf(val);
          } else {
            ((float*)Cout)[((size_t)gm << 10) + gn] = val;
          }
        }
      }
  } else {
    // MODE 1: transpose quadrant via per-wave LDS region, store coalesced [B,H,dk,S]
    short* wl = (short*)(void*)lds + w * 4096;  // [64 n][64 m]
#pragma unroll
    for (int mf = 0; mf < 4; ++mf)
#pragma unroll
      for (int nf = 0; nf < 4; ++nf) {
        int nl = nf * 16 + lx;
        float bvl = bias[n0 + wc * 64 + nl];
#pragma unroll
        for (int r = 0; r < 4; ++r) {
          int ml = mf * 16 + lg * 4 + r;
          wl[nl * 64 + ml] = f2bf((acc[mf][nf][r] + bvl) * scl);
        }
      }
    short* Cs = (short*)Cout;
#pragma unroll
    for (int p = 0; p < 8; ++p) {
      int d  = p * 8 + (lane >> 3);
      int mm = (lane & 7) * 8;
      bf16x4 lo = *(const bf16x4*)(wl + d * 64 + mm);
      bf16x4 hi = *(const bf16x4*)(wl + d * 64 + mm + 4);
      int gn = n0 + wc * 64 + d;
      int h = gn >> 6, dk = gn & 63;
      int gm = m0 + wr * 64 + mm;
      int bb = gm >> 11, s = gm & 2047;
      short8 val = { lo[0], lo[1], lo[2], lo[3], hi[0], hi[1], hi[2], hi[3] };
      *(short8*)(Cs + ((size_t)(bb * 16 + h) << 17) + ((size_t)dk << 11) + s) = val;
    }
  }
}

// fused Q/K/V projections: blocks [0,512) Q, [512,1024) K, [1024,1536) V
__launch_bounds__(256, 3)
__global__ void proj_k(const float* __restrict__ qA, const float* __restrict__ kA,
                       const float* __restrict__ vA,
                       const short* __restrict__ wq, const short* __restrict__ wk,
                       const short* __restrict__ wv,
                       const float* __restrict__ bq, const float* __restrict__ bk,
                       const float* __restrict__ bv,
                       short* __restrict__ Qb, short* __restrict__ Kb,
                       short* __restrict__ Vtb, float qs)
{
  __shared__ __align__(16) char lds[49152];
  const int gid = blockIdx.x;
  const int which = gid >> 9, L = gid & 511;
  if (which == 0)      gemm_body<0>(lds, qA, wq, bq, Qb, qs, L);
  else if (which == 1) gemm_body<0>(lds, kA, wk, bk, Kb, 1.0f, L);
  else                 gemm_body<1>(lds, vA, wv, bv, Vtb, 1.0f, L);
}

__launch_bounds__(256, 3)
__global__ void outproj_k(const short* __restrict__ Xb, const short* __restrict__ wo,
                          const float* __restrict__ bo, void* __restrict__ out)
{
  __shared__ __align__(16) char lds[49152];
  gemm_body<2>(lds, Xb, wo, bo, out, 1.0f, blockIdx.x);
}

// ---------------- flash attention (round-8 verified structure) ----------------
// 1-D grid 1024, XCD-swizzled: the 16 q-tile blocks sharing one bh's K/V panel
// cluster on one XCD. 4 waves x 32 q-rows = 128 rows/block.
// Q pre-scaled by log2(e)/sqrt(dk) at projection -> scores already in exp2 domain.
// K and V double-buffered: stage NEXT tile at top, compute current, ONE barrier
// per tile. (Single-buffer V / direct-V / 8-wave variants all raced — R5-R11.)
__launch_bounds__(256, 3)
__global__ void attn_k(const short* __restrict__ Qb, const short* __restrict__ Kb,
                       const short* __restrict__ Vtb, short* __restrict__ Xb)
{
  __shared__ __align__(16) char lds[49152];
  char* Pb = lds + 32768;      // [128 q][64 kv] bf16, slot ^= (row&7)
  const int tid = threadIdx.x, lane = tid & 63, w = tid >> 6;
  const int lx = lane & 15, lg = lane >> 4;
  const int L  = blockIdx.x;                  // 0..1023
  const int q0 = ((L >> 3) & 15) * 128;
  const int bh = ((L >> 7) << 3) | (L & 7);
  const size_t base = (size_t)bh << 17;       // *131072

  bf16x8 aq[2][2];
#pragma unroll
  for (int m = 0; m < 2; ++m)
#pragma unroll
    for (int ks = 0; ks < 2; ++ks)
      aq[m][ks] = *(const bf16x8*)(Qb + base + (size_t)(q0 + w * 32 + m * 16 + lx) * 64 + ks * 32 + lg * 8);

  f32x4 o[2][4];
  f32x4 lrun[2];
  float mrun = -1e30f;
#pragma unroll
  for (int m = 0; m < 2; ++m) {
#pragma unroll
    for (int df = 0; df < 4; ++df) o[m][df] = 0.f;
    lrun[m] = 0.f;
  }
  const bf16x8 vones = { 0x3F80, 0x3F80, 0x3F80, 0x3F80, 0x3F80, 0x3F80, 0x3F80, 0x3F80 };

  // prologue: stage tile 0 into buf 0
#pragma unroll
  for (int i = 0; i < 2; ++i) {
    int task = i * 256 + tid;
    int row = task >> 3, sl = task & 7, sg = sl ^ (row & 7);
    gload16(Kb + base + (size_t)row * 64 + sg * 8, lds + (i * 256 + w * 64) * 16);
    gload16(Vtb + base + (size_t)row * 2048 + sg * 8, lds + 16384 + (i * 256 + w * 64) * 16);
  }
  __syncthreads();

  for (int kt = 0; kt < 32; ++kt) {
    char* Kcur = lds + (kt & 1) * 8192;
    char* Vcur = lds + 16384 + (kt & 1) * 8192;
    if (kt < 31) {
      const int kv1 = (kt + 1) * 64;
      char* Knxt = lds + ((kt + 1) & 1) * 8192;
      char* Vnxt = lds + 16384 + ((kt + 1) & 1) * 8192;
#pragma unroll
      for (int i = 0; i < 2; ++i) {
        int task = i * 256 + tid;
        int row = task >> 3, sl = task & 7, sg = sl ^ (row & 7);
        gload16(Kb + base + (size_t)(kv1 + row) * 64 + sg * 8, Knxt + (i * 256 + w * 64) * 16);
        gload16(Vtb + base + (size_t)row * 2048 + kv1 + sg * 8, Vnxt + (i * 256 + w * 64) * 16);
      }
    }

    // S = Q K^T (already in exp2 domain; Q pre-scaled)
    f32x4 sc[2][4];
#pragma unroll
    for (int m = 0; m < 2; ++m)
#pragma unroll
      for (int nf = 0; nf < 4; ++nf) sc[m][nf] = 0.f;
    __builtin_amdgcn_s_setprio(1);
#pragma unroll
    for (int ks = 0; ks < 2; ++ks) {
      bf16x8 bk[4];
#pragma unroll
      for (int nf = 0; nf < 4; ++nf) {
        int kr = nf * 16 + lx;
        int sl = (ks * 4 + lg) ^ (kr & 7);
        bk[nf] = *(const bf16x8*)(Kcur + kr * 128 + sl * 16);
      }
#pragma unroll
      for (int m = 0; m < 2; ++m)
#pragma unroll
        for (int nf = 0; nf < 4; ++nf)
          sc[m][nf] = __builtin_amdgcn_mfma_f32_16x16x32_bf16(aq[m][ks], bk[nf], sc[m][nf], 0, 0, 0);
    }
    __builtin_amdgcn_s_setprio(0);

    // wave-global tile max (upper-bounds every row max in this wave)
    f32x4 v0 = vmax4(sc[0][0], sc[0][1]);
    f32x4 v1 = vmax4(sc[0][2], sc[0][3]);
    f32x4 v2 = vmax4(sc[1][0], sc[1][1]);
    f32x4 v3 = vmax4(sc[1][2], sc[1][3]);
    v0 = vmax4(vmax4(v0, v1), vmax4(v2, v3));
    float mx = fmaxf(fmaxf(v0[0], v0[1]), fmaxf(v0[2], v0[3]));
    mx = fmaxf(mx, __shfl_xor(mx, 1));
    mx = fmaxf(mx, __shfl_xor(mx, 2));
    mx = fmaxf(mx, __shfl_xor(mx, 4));
    mx = fmaxf(mx, __shfl_xor(mx, 8));
    mx = fmaxf(mx, __shfl_xor(mx, 16));
    mx = fmaxf(mx, __shfl_xor(mx, 32));
    const float mn = fmaxf(mrun, mx);
    const float al = EXP2F(mrun - mn);
    mrun = mn;
    if (al < 1.0f) {   // wave-uniform: rescale only when max grew
#pragma unroll
      for (int m = 0; m < 2; ++m) {
#pragma unroll
        for (int df = 0; df < 4; ++df) o[m][df] *= al;
        lrun[m] *= al;
      }
    }
    const float nm = -mn;

    // P = exp2(S - mn) -> bf16 (cvt_pk) -> Plds (XOR-swizzled rows, wave-private)
#pragma unroll
    for (int m = 0; m < 2; ++m)
#pragma unroll
      for (int nf = 0; nf < 4; ++nf) {
        f32x4 p;
#pragma unroll
        for (int r = 0; r < 4; ++r) p[r] = EXP2F(sc[m][nf][r] + nm);
        uint32_t ab = cvtpk(p[0], p[1]);
        uint32_t cd = cvtpk(p[2], p[3]);
        short v4[4] = { (short)ab, (short)(ab >> 16), (short)cd, (short)(cd >> 16) };
#pragma unroll
        for (int r = 0; r < 4; ++r) {
          int row = w * 32 + m * 16 + lg * 4 + r;
          int slot = (nf * 2 + (lx >> 3)) ^ (row & 7);
          *(short*)(Pb + row * 128 + slot * 16 + (lx & 7) * 2) = v4[r];
        }
      }

    // O += P V ; row-sums via all-ones B fragment
    f32x4 rs0 = 0.f, rs1 = 0.f;
#pragma unroll
    for (int ks = 0; ks < 2; ++ks) {
      bf16x8 pa[2], bvv[4];
#pragma unroll
      for (int m = 0; m < 2; ++m) {
        int row = w * 32 + m * 16 + lx;
        int sl = (ks * 4 + lg) ^ (row & 7);
        pa[m] = *(const bf16x8*)(Pb + row * 128 + sl * 16);
      }
#pragma unroll
      for (int df = 0; df < 4; ++df) {
        int dr = df * 16 + lx;
        int sl = (ks * 4 + lg) ^ (dr & 7);
        bvv[df] = *(const bf16x8*)(Vcur + dr * 128 + sl * 16);
      }
      __builtin_amdgcn_s_setprio(1);
      rs0 = __builtin_amdgcn_mfma_f32_16x16x32_bf16(pa[0], vones, rs0, 0, 0, 0);
      rs1 = __builtin_amdgcn_mfma_f32_16x16x32_bf16(pa[1], vones, rs1, 0, 0, 0);
#pragma unroll
      for (int m = 0; m < 2; ++m)
#pragma unroll
        for (int df = 0; df < 4; ++df)
          o[m][df] = __builtin_amdgcn_mfma_f32_16x16x32_bf16(pa[m], bvv[df], o[m][df], 0, 0, 0);
      __builtin_amdgcn_s_setprio(0);
    }
    lrun[0] += rs0;
    lrun[1] += rs1;

    __syncthreads();   // staged next tile complete + all waves done with cur bufs
  }

  // epilogue: O / l  -> X [B,S,1024] bf16 (merged heads)
  const int bb = bh >> 4, h = bh & 15;
#pragma unroll
  for (int m = 0; m < 2; ++m)
#pragma unroll
    for (int r = 0; r < 4; ++r) {
      float inv = 1.0f / lrun[m][r];
      int gs = q0 + w * 32 + m * 16 + lg * 4 + r;
      size_t rowb = ((size_t)(bb * 2048 + gs)) << 10;
#pragma unroll
      for (int df = 0; df < 4; ++df)
        Xb[rowb + h * 64 + df * 16 + lx] = f2bf(o[m][df][r] * inv);
    }
}

// ---------------- host ----------------
extern "C" void kernel_launch(void* const* d_in, const int* in_sizes, int n_in,
                              void* d_out, int out_size, void* d_ws, size_t ws_size,
                              hipStream_t stream)
{
  (void)in_sizes; (void)n_in; (void)out_size; (void)ws_size;
  const float* q  = (const float*)d_in[0];
  const float* k  = (const float*)d_in[1];
  const float* v  = (const float*)d_in[2];
  const float* Wq = (const float*)d_in[3];
  const float* bq = (const float*)d_in[4];
  const float* Wk = (const float*)d_in[5];
  const float* bk = (const float*)d_in[6];
  const float* Wv = (const float*)d_in[7];
  const float* bv = (const float*)d_in[8];
  const float* Wo = (const float*)d_in[9];
  const float* bo = (const float*)d_in[10];

  short* ws  = (short*)d_ws;
  short* wqb = ws;                  // 1024*1024 each
  short* wkb = wqb + 1048576;
  short* wvb = wkb + 1048576;
  short* wob = wvb + 1048576;
  short* Qb  = wob + 1048576;       // 8192*1024 each
  short* Kb  = Qb  + 8388608;
  short* Vtb = Kb  + 8388608;
  short* Xb  = Vtb + 8388608;       // total 75,497,472 bytes

  const float QSCALE = 0.18033688011112042f;  // log2(e)/sqrt(64)

  cvtw_k<<<dim3(1024, 4), 256, 0, stream>>>(Wq, Wk, Wv, Wo, wqb);
  proj_k<<<1536, 256, 0, stream>>>(q, k, v, wqb, wkb, wvb, bq, bk, bv,
                                   Qb, Kb, Vtb, QSCALE);
  attn_k<<<1024, 256, 0, stream>>>(Qb, Kb, Vtb, Xb);
  outproj_k<<<512, 256, 0, stream>>>(Xb, wob, bo, d_out);
}